// Round 3
// baseline (9554.115 us; speedup 1.0000x reference)
//
#include <hip/hip_runtime.h>
#include <cmath>

namespace {

constexpr int kB = 64;
constexpr int kL = 2048;
constexpr int kH = 512;
constexpr int kN = 64;

// ---------------------------------------------------------------------------
// Twiddle table: twst[(1<<(s-1))-1 + j] = exp(-2*pi*i*j / (1<<s)), s = 1..12.
// Stages 1..11 drive the 2048-pt FFT; the s=12 block (offset 2047, 2048
// entries) is exp(-2*pi*i*k/4096) for the real-FFT unpack/repack.
// ---------------------------------------------------------------------------
__global__ __launch_bounds__(256) void twiddle_init_kernel(float2* __restrict__ twst)
{
  int idx = blockIdx.x * 256 + threadIdx.x;
  if (idx >= 4095) return;
  int v  = idx + 1;
  int fl = 31 - __clz(v);          // v in [2^fl, 2^(fl+1))
  int j  = v - (1 << fl);
  int len = 1 << (fl + 1);
  double ang = -6.283185307179586476925286766559 * (double)j / (double)len;
  twst[idx] = make_float2((float)cos(ang), (float)sin(ang));
}

// ---------------------------------------------------------------------------
// 2048-point complex FFT in LDS. radix-2 DIT, bit-reversed input permutation,
// natural-order output. 256 threads, 4 butterflies/thread/stage.
// ---------------------------------------------------------------------------
__device__ __forceinline__ void fft2048_lds(float* re, float* im,
                                            const float2* twsl, int tid)
{
  for (int idx = tid; idx < 2048; idx += 256) {
    int r = (int)(__brev((unsigned)idx) >> 21);
    if (r > idx) {
      float a = re[idx]; re[idx] = re[r]; re[r] = a;
      float b = im[idx]; im[idx] = im[r]; im[r] = b;
    }
  }
  __syncthreads();
  for (int s = 1; s <= 11; s++) {
    int half = 1 << (s - 1);
    #pragma unroll
    for (int w = 0; w < 4; w++) {
      int bf = tid + (w << 8);
      int j  = bf & (half - 1);
      int g  = bf >> (s - 1);
      int p0 = (g << s) + j;
      int p1 = p0 + half;
      float2 tw = twsl[half - 1 + j];
      float xr = re[p1], xi = im[p1];
      float tr = xr * tw.x - xi * tw.y;
      float ti = xr * tw.y + xi * tw.x;
      float ur = re[p0], ui = im[p0];
      re[p0] = ur + tr; im[p0] = ui + ti;
      re[p1] = ur - tr; im[p1] = ui - ti;
    }
    __syncthreads();
  }
}

// ---------------------------------------------------------------------------
// Encoder (chunk): X[bc][h][l] = sum_d seq[bc][l][d]*encW[d][h] + encb[h]
// ---------------------------------------------------------------------------
__global__ __launch_bounds__(256) void encoder_kernel(
    const float* __restrict__ seq, const float* __restrict__ encW,
    const float* __restrict__ encb, float* __restrict__ X)
{
  int bid = blockIdx.x;
  int lt = bid & 7;
  int h  = (bid >> 3) & 511;
  int bc = bid >> 12;              // local chunk batch
  int l  = lt * 256 + threadIdx.x;
  const float* sp = seq + ((size_t)bc * kL + l) * 5;
  float acc = encb[h];
  #pragma unroll
  for (int d = 0; d < 5; d++) acc += sp[d] * encW[d * kH + h];
  X[((size_t)bc * kH + h) * kL + l] = acc;
}

// ---------------------------------------------------------------------------
// LN stats over H per (bc,l): mu, rstd. grid: CB*32; block 256 = 4 hg x 64 l
// ---------------------------------------------------------------------------
__global__ __launch_bounds__(256) void ln_stats_kernel(
    const float* __restrict__ X, float* __restrict__ mu, float* __restrict__ rstd)
{
  int b  = blockIdx.x >> 5;        // local chunk batch
  int l0 = (blockIdx.x & 31) * 64;
  int g  = threadIdx.x >> 6;
  int lt = threadIdx.x & 63;
  const float* xb = X + (size_t)b * kH * kL + l0 + lt;
  float s = 0.f, q = 0.f;
  for (int h = g; h < kH; h += 4) {
    float v = xb[(size_t)h * kL];
    s += v; q += v * v;
  }
  __shared__ float ss[4][64], qq[4][64];
  ss[g][lt] = s; qq[g][lt] = q;
  __syncthreads();
  if (threadIdx.x < 64) {
    float S = ss[0][threadIdx.x] + ss[1][threadIdx.x] + ss[2][threadIdx.x] + ss[3][threadIdx.x];
    float Q = qq[0][threadIdx.x] + qq[1][threadIdx.x] + qq[2][threadIdx.x] + qq[3][threadIdx.x];
    float m   = S * (1.f / kH);
    float var = Q * (1.f / kH) - m * m;
    mu[b * kL + l0 + threadIdx.x]   = m;
    rstd[b * kL + l0 + threadIdx.x] = 1.f / sqrtf(var + 1e-5f);
  }
}

// ---------------------------------------------------------------------------
// Per-(layer,h,n) SSM coefficients for ALL 4 layers at once:
// w = dt*A (complex), cc = 2*C*dB (complex). grid 512 x 256 = 131072 = 4*H*N
// ---------------------------------------------------------------------------
__global__ __launch_bounds__(256) void coeff_kernel(
    const float* __restrict__ logst, const float* __restrict__ Are,
    const float* __restrict__ Aim, const float* __restrict__ Bre,
    const float* __restrict__ Bim, const float* __restrict__ Cp,
    float4* __restrict__ coeff)
{
  int idx = blockIdx.x * 256 + threadIdx.x;   // (layer*512 + h)*64 + n
  float dt = expf(logst[idx >> 6]);           // logst is [4][512] flat
  float ar = -expf(Are[idx]);
  float ai = Aim[idx];
  float wre = dt * ar, wim = dt * ai;
  float er  = expf(wre);
  float dAr = er * cosf(wim), dAi = er * sinf(wim);
  float numr = dAr - 1.f, numi = dAi;
  float den  = ar * ar + ai * ai;
  float qr = (numr * ar + numi * ai) / den;     // (dA-1)/A
  float qi = (numi * ar - numr * ai) / den;
  float br = Bre[idx], bi = Bim[idx];
  float tr = dt * (br * qr - bi * qi);          // dB
  float ti = dt * (br * qi + bi * qr);
  float cr = Cp[2 * idx], ci = Cp[2 * idx + 1];
  float ccr = 2.f * (cr * tr - ci * ti);        // 2*C*dB
  float cci = 2.f * (cr * ti + ci * tr);
  coeff[idx] = make_float4(wre, wim, ccr, cci);
}

// ---------------------------------------------------------------------------
// SSM kernel row k[l] = Re(sum_n cc*exp(w*l)), then half-spectrum of its
// length-4096 zero-padded rFFT. One block per grid row (layer*h or h).
// ---------------------------------------------------------------------------
__global__ __launch_bounds__(256) void kfft_kernel(
    const float4* __restrict__ coeff, const float2* __restrict__ twst,
    float2* __restrict__ Kf)
{
  __shared__ float sm[2048 * 2 + 2047 * 2];
  float* cre  = sm;
  float* cim  = sm + 2048;
  float2* twsl = (float2*)(sm + 4096);
  int tid = threadIdx.x;
  int row = blockIdx.x;
  for (int idx = tid; idx < 2047; idx += 256) twsl[idx] = twst[idx];
  float kreg[8] = {0.f, 0.f, 0.f, 0.f, 0.f, 0.f, 0.f, 0.f};
  const float4* ch = coeff + (size_t)row * kN;
  for (int n = 0; n < kN; n++) {
    float4 c = ch[n];
    #pragma unroll
    for (int i = 0; i < 8; i++) {
      float l = (float)(i * 256 + tid);
      float e = expf(c.x * l);
      float sn, cs;
      sincosf(c.y * l, &sn, &cs);
      kreg[i] += e * (c.z * cs - c.w * sn);
    }
  }
  // pack real k (zero-padded to 4096) into 2048 complex: c[j] = k[2j]+i*k[2j+1]
  #pragma unroll
  for (int i = 0; i < 8; i++) {
    int j = i * 128 + (tid >> 1);
    if (tid & 1) cim[j] = kreg[i]; else cre[j] = kreg[i];
  }
  for (int j = 1024 + tid; j < 2048; j += 256) { cre[j] = 0.f; cim[j] = 0.f; }
  __syncthreads();
  fft2048_lds(cre, cim, twsl, tid);
  // unpack: U[k] = Fe[k] + w4096^k * Fo[k]
  float2* kfh = Kf + (size_t)row * 2049;
  #pragma unroll
  for (int i = 0; i < 8; i++) {
    int k  = i * 256 + tid;
    int mk = (2048 - k) & 2047;
    float ar = cre[k], ai2 = cim[k], br = cre[mk], bi = cim[mk];
    float fer = 0.5f * (ar + br),  fei = 0.5f * (ai2 - bi);
    float fo_r = 0.5f * (ai2 + bi), foi = 0.5f * (br - ar);
    float2 w = twst[2047 + k];
    kfh[k] = make_float2(fer + w.x * fo_r - w.y * foi,
                         fei + w.x * foi + w.y * fo_r);
  }
  if (tid == 0) kfh[2048] = make_float2(cre[0] - cim[0], 0.f);
}

// ---------------------------------------------------------------------------
// Fused: inline LN apply -> rFFT(z) -> x Kf -> irFFT -> +D*z -> GELU -> Y
// one block per (bc,h) row. LDS: 48 KB
// ---------------------------------------------------------------------------
__global__ __launch_bounds__(256) void conv_kernel(
    const float* __restrict__ X, const float* __restrict__ mu,
    const float* __restrict__ rstd, const float* __restrict__ gam,
    const float* __restrict__ bet, const float* __restrict__ Dp,
    const float2* __restrict__ Kf, const float2* __restrict__ twst,
    float* __restrict__ Y)
{
  __shared__ float sm[12288];
  float* cre = sm;
  float* cim = sm + 2048;
  float* Ure = sm + 4096;   // 2049
  float* Uim = sm + 6145;   // 2049
  float2* twsl = (float2*)(sm + 8194);  // 2047 float2
  int tid = threadIdx.x;
  int bid = blockIdx.x;          // bc*512 + h
  int b = bid >> 9, h = bid & 511;
  for (int idx = tid; idx < 2047; idx += 256) twsl[idx] = twst[idx];
  const float* xrow  = X + (size_t)bid * kL;
  const float* murow = mu + b * kL;
  const float* rrow  = rstd + b * kL;
  float gam_h = gam[h], bet_h = bet[h], d_h = Dp[h];
  float zreg[8];
  #pragma unroll
  for (int i = 0; i < 8; i++) {
    int l = i * 256 + tid;
    zreg[i] = (xrow[l] - murow[l]) * rrow[l] * gam_h + bet_h;
  }
  // pack z (zero-padded to 4096)
  #pragma unroll
  for (int i = 0; i < 8; i++) {
    int j = i * 128 + (tid >> 1);
    if (tid & 1) cim[j] = zreg[i]; else cre[j] = zreg[i];
  }
  for (int j = 1024 + tid; j < 2048; j += 256) { cre[j] = 0.f; cim[j] = 0.f; }
  __syncthreads();
  fft2048_lds(cre, cim, twsl, tid);
  // unpack to half-spectrum U[0..2048]
  #pragma unroll
  for (int i = 0; i < 8; i++) {
    int k  = i * 256 + tid;
    int mk = (2048 - k) & 2047;
    float ar = cre[k], ai2 = cim[k], br = cre[mk], bi = cim[mk];
    float fer = 0.5f * (ar + br),  fei = 0.5f * (ai2 - bi);
    float fo_r = 0.5f * (ai2 + bi), foi = 0.5f * (br - ar);
    float2 w = twst[2047 + k];
    Ure[k] = fer + w.x * fo_r - w.y * foi;
    Uim[k] = fei + w.x * foi + w.y * fo_r;
  }
  if (tid == 0) { Ure[2048] = cre[0] - cim[0]; Uim[2048] = 0.f; }
  __syncthreads();
  // P = U*Kf ; repack C'[k] = E' + i O' ; store conj(C') for inverse-by-conj
  const float2* kfh = Kf + (size_t)h * 2049;
  #pragma unroll
  for (int i = 0; i < 8; i++) {
    int k  = i * 256 + tid;
    int mk = 2048 - k;
    float2 k1 = kfh[k], k2 = kfh[mk];
    float Ukr = Ure[k],  Uki = Uim[k];
    float Umr = Ure[mk], Umi = Uim[mk];
    float Pr = Ukr * k1.x - Uki * k1.y, Pi = Ukr * k1.y + Uki * k1.x;
    float Qr = Umr * k2.x - Umi * k2.y, Qi = Umr * k2.y + Umi * k2.x;
    float epr = 0.5f * (Pr + Qr), epi = 0.5f * (Pi - Qi);
    float dr  = 0.5f * (Pr - Qr), di  = 0.5f * (Pi + Qi);
    float2 w = twst[2047 + k];
    float opr = w.x * dr + w.y * di;     // w^{-k} * (..)
    float opi = w.x * di - w.y * dr;
    cre[k] = epr - opi;                  // Re C'
    cim[k] = -(epi + opr);               // -Im C'  (conj)
  }
  __syncthreads();
  fft2048_lds(cre, cim, twsl, tid);
  // y[2j] = Re/2048, y[2j+1] = -Im/2048 ; then skip D*z, exact GELU
  float* yrow = Y + (size_t)bid * kL;
  constexpr float inv = 1.f / 2048.f;
  #pragma unroll
  for (int i = 0; i < 8; i++) {
    int l = i * 256 + tid;
    int j = i * 128 + (tid >> 1);
    float v = (tid & 1) ? (-cim[j]) : cre[j];
    v = v * inv + d_h * zreg[i];
    yrow[l] = 0.5f * v * (1.f + erff(v * 0.70710678f));
  }
}

// ---------------------------------------------------------------------------
// X[bc][ho][l] += bias[ho] + sum_hi W[hi][ho] * Y[bc][hi][l]  (residual)
// block tile 128(ho) x 64(l), K-chunk 16, 8x4 per thread. fp32 vector ALU.
// ---------------------------------------------------------------------------
__global__ __launch_bounds__(256) void gemm_kernel(
    const float* __restrict__ Y, const float* __restrict__ W,
    const float* __restrict__ bias, float* __restrict__ X)
{
  __shared__ float Wt[16][128];
  __shared__ float Yt[16][64];
  int b  = blockIdx.z;             // local chunk batch
  int mo = blockIdx.y * 128;
  int no = blockIdx.x * 64;
  int tid = threadIdx.x;
  int ty = tid >> 4, tx = tid & 15;
  const float* Yb = Y + (size_t)b * kH * kL;
  float acc[8][4];
  #pragma unroll
  for (int i = 0; i < 8; i++)
    #pragma unroll
    for (int j = 0; j < 4; j++) acc[i][j] = 0.f;
  for (int k0 = 0; k0 < kH; k0 += 16) {
    #pragma unroll
    for (int i = 0; i < 8; i++) {
      int idx = tid + i * 256;
      Wt[idx >> 7][idx & 127] = W[(size_t)(k0 + (idx >> 7)) * kH + mo + (idx & 127)];
    }
    #pragma unroll
    for (int i = 0; i < 4; i++) {
      int idx = tid + i * 256;
      Yt[idx >> 6][idx & 63] = Yb[(size_t)(k0 + (idx >> 6)) * kL + no + (idx & 63)];
    }
    __syncthreads();
    #pragma unroll
    for (int kk = 0; kk < 16; kk++) {
      float a[8], bv[4];
      #pragma unroll
      for (int i = 0; i < 8; i++) a[i] = Wt[kk][ty * 8 + i];
      #pragma unroll
      for (int j = 0; j < 4; j++) bv[j] = Yt[kk][tx * 4 + j];
      #pragma unroll
      for (int i = 0; i < 8; i++)
        #pragma unroll
        for (int j = 0; j < 4; j++) acc[i][j] += a[i] * bv[j];
    }
    __syncthreads();
  }
  #pragma unroll
  for (int i = 0; i < 8; i++) {
    int ho = mo + ty * 8 + i;
    float bb = bias[ho];
    float* xr = X + ((size_t)b * kH + ho) * kL + no + tx * 4;
    #pragma unroll
    for (int j = 0; j < 4; j++) xr[j] += acc[i][j] + bb;
  }
}

// ---------------------------------------------------------------------------
// pooled[row] = mean_l X[row][l]   (row = bc*512+h, output offset by chunk)
// ---------------------------------------------------------------------------
__global__ __launch_bounds__(256) void pool_kernel(const float* __restrict__ X,
                                                   float* __restrict__ pooled)
{
  int bid = blockIdx.x;
  const float* row = X + (size_t)bid * kL;
  float s = 0.f;
  for (int i = threadIdx.x; i < kL; i += 256) s += row[i];
  for (int off = 32; off > 0; off >>= 1) s += __shfl_down(s, off);
  __shared__ float p[4];
  if ((threadIdx.x & 63) == 0) p[threadIdx.x >> 6] = s;
  __syncthreads();
  if (threadIdx.x == 0) pooled[bid] = (p[0] + p[1] + p[2] + p[3]) * (1.f / kL);
}

// ---------------------------------------------------------------------------
// fusion MLP + two heads. one block per b (full batch).
// ---------------------------------------------------------------------------
__global__ __launch_bounds__(256) void head_kernel(
    const float* __restrict__ pooled, const int* __restrict__ com,
    const int* __restrict__ cou, const float* __restrict__ comE,
    const float* __restrict__ couE, const float* __restrict__ fusW,
    const float* __restrict__ fusb, const float* __restrict__ vW1,
    const float* __restrict__ vb1, const float* __restrict__ vW2,
    const float* __restrict__ vb2, const float* __restrict__ wW1,
    const float* __restrict__ wb1, const float* __restrict__ wW2,
    const float* __restrict__ wb2, float* __restrict__ out)
{
  __shared__ float feat[768];
  __shared__ float h1[512];
  __shared__ float vv[256];
  int tid = threadIdx.x;
  int b = blockIdx.x;
  int cid = com[b], ct = cou[b];
  for (int i = tid; i < 512; i += 256) feat[i] = pooled[b * kH + i];
  if (tid < 128) {
    feat[512 + tid] = comE[cid * 128 + tid];
    feat[640 + tid] = couE[ct * 128 + tid];
  }
  __syncthreads();
  #pragma unroll
  for (int jj = 0; jj < 2; jj++) {
    int j = tid + jj * 256;
    float acc = fusb[j];
    for (int i = 0; i < 768; i++) acc += feat[i] * fusW[i * kH + j];
    h1[j] = acc;
  }
  __syncthreads();
  {
    float acc = vb1[tid];
    for (int i = 0; i < 512; i++) acc += h1[i] * vW1[i * 256 + tid];
    vv[tid] = fmaxf(acc, 0.f) * vW2[tid];
  }
  __syncthreads();
  for (int s = 128; s > 0; s >>= 1) {
    if (tid < s) vv[tid] += vv[tid + s];
    __syncthreads();
  }
  if (tid == 0) out[b * 2 + 0] = vv[0] + vb2[0];
  __syncthreads();
  {
    float acc = wb1[tid];
    for (int i = 0; i < 512; i++) acc += h1[i] * wW1[i * 256 + tid];
    vv[tid] = fmaxf(acc, 0.f) * wW2[tid];
  }
  __syncthreads();
  for (int s = 128; s > 0; s >>= 1) {
    if (tid < s) vv[tid] += vv[tid + s];
    __syncthreads();
  }
  if (tid == 0) out[b * 2 + 1] = vv[0] + wb2[0];
}

}  // namespace

extern "C" void kernel_launch(void* const* d_in, const int* in_sizes, int n_in,
                              void* d_out, int out_size, void* d_ws, size_t ws_size,
                              hipStream_t stream)
{
  (void)in_sizes; (void)n_in; (void)out_size;
  const float* seq   = (const float*)d_in[0];
  const int*   com   = (const int*)d_in[1];
  const int*   cou   = (const int*)d_in[2];
  const float* encW  = (const float*)d_in[3];
  const float* encb  = (const float*)d_in[4];
  const float* comE  = (const float*)d_in[5];
  const float* couE  = (const float*)d_in[6];
  const float* logst = (const float*)d_in[7];
  const float* Ar    = (const float*)d_in[8];
  const float* Ai    = (const float*)d_in[9];
  const float* Br    = (const float*)d_in[10];
  const float* Bi    = (const float*)d_in[11];
  const float* Cp    = (const float*)d_in[12];
  const float* Dp    = (const float*)d_in[13];
  const float* outW  = (const float*)d_in[14];
  const float* outb  = (const float*)d_in[15];
  const float* lng   = (const float*)d_in[16];
  const float* lnb   = (const float*)d_in[17];
  const float* fusW  = (const float*)d_in[18];
  const float* fusb  = (const float*)d_in[19];
  const float* vW1   = (const float*)d_in[20];
  const float* vb1   = (const float*)d_in[21];
  const float* vW2   = (const float*)d_in[22];
  const float* vb2   = (const float*)d_in[23];
  const float* wW1   = (const float*)d_in[24];
  const float* wb1   = (const float*)d_in[25];
  const float* wW2   = (const float*)d_in[26];
  const float* wb2   = (const float*)d_in[27];
  float* out = (float*)d_out;

  // ---- adaptive workspace sizing (floats) ----
  const size_t F_KF1   = (size_t)kH * 2049 * 2;     // one layer's spectrum
  const size_t F_COEFF = (size_t)4 * kH * kN * 4;   // all-layer coeffs (float4)
  const size_t F_TW    = 8190;
  const size_t F_POOL  = (size_t)kB * kH;
  size_t nws = ws_size / sizeof(float);
  auto need = [&](size_t cb, bool kfall) -> size_t {
    return (kfall ? 4 : 1) * F_KF1 + F_COEFF + F_TW + F_POOL
         + 2 * cb * (size_t)kL            // mu + rstd
         + 2 * cb * (size_t)kH * kL;      // X + Y
  };
  const int cand[7] = {64, 32, 16, 8, 4, 2, 1};
  int CB = 0; bool kfAll = true;
  for (int i = 0; i < 7 && !CB; i++)
    if (need(cand[i], true) <= nws) { CB = cand[i]; kfAll = true; }
  for (int i = 0; i < 7 && !CB; i++)
    if (need(cand[i], false) <= nws) { CB = cand[i]; kfAll = false; }
  if (!CB) { CB = 1; kfAll = false; }   // floor (~17 MiB)

  float* ws = (float*)d_ws;
  size_t o = 0;
  float2* Kf    = (float2*)(ws + o); o += (kfAll ? 4 : 1) * F_KF1;
  float4* coeff = (float4*)(ws + o); o += F_COEFF;
  float2* twst  = (float2*)(ws + o); o += F_TW;
  float*  pooled= ws + o;            o += F_POOL;
  float*  mu    = ws + o;            o += (size_t)CB * kL;
  float*  rstd  = ws + o;            o += (size_t)CB * kL;
  float*  X     = ws + o;            o += (size_t)CB * kH * kL;
  float*  Yb    = ws + o;            o += (size_t)CB * kH * kL;

  twiddle_init_kernel<<<16, 256, 0, stream>>>(twst);
  coeff_kernel<<<512, 256, 0, stream>>>(logst, Ar, Ai, Br, Bi, Cp, coeff);
  if (kfAll) kfft_kernel<<<4 * kH, 256, 0, stream>>>(coeff, twst, Kf);

  const int nchunk = kB / CB;
  for (int c = 0; c < nchunk; c++) {
    const int b0 = c * CB;
    encoder_kernel<<<CB * kH * (kL / 256), 256, 0, stream>>>(
        seq + (size_t)b0 * kL * 5, encW, encb, X);
    for (int layer = 0; layer < 4; layer++) {
      if (!kfAll)
        kfft_kernel<<<kH, 256, 0, stream>>>(
            coeff + (size_t)layer * kH * kN, twst, Kf);
      ln_stats_kernel<<<CB * (kL / 64), 256, 0, stream>>>(X, mu, rstd);
      conv_kernel<<<CB * kH, 256, 0, stream>>>(
          X, mu, rstd, lng + layer * kH, lnb + layer * kH, Dp + layer * kH,
          kfAll ? Kf + (size_t)layer * kH * 2049 : Kf, twst, Yb);
      gemm_kernel<<<dim3(kL / 64, kH / 128, CB), 256, 0, stream>>>(
          Yb, outW + (size_t)layer * kH * kH, outb + layer * kH, X);
    }
    pool_kernel<<<CB * kH, 256, 0, stream>>>(X, pooled + (size_t)b0 * kH);
  }

  head_kernel<<<kB, 256, 0, stream>>>(pooled, com, cou, comE, couE, fusW, fusb,
                                      vW1, vb1, vW2, vb2, wW1, wb1, wW2, wb2, out);
}

// Round 4
// 7689.760 us; speedup vs baseline: 1.2424x; 1.2424x over previous
//
#include <hip/hip_runtime.h>
#include <cmath>

namespace {

constexpr int kB = 64;
constexpr int kL = 2048;
constexpr int kH = 512;
constexpr int kN = 64;

typedef short s16x8 __attribute__((ext_vector_type(8)));
typedef float f32x4 __attribute__((ext_vector_type(4)));

// bf16 round-to-nearest-even split: f ~= hi + lo (both bf16)
__device__ __forceinline__ void bf16_split(float f, unsigned short& hi, unsigned short& lo)
{
  unsigned u = __float_as_uint(f);
  unsigned rh = u + 0x7FFFu + ((u >> 16) & 1u);
  hi = (unsigned short)(rh >> 16);
  float fh = __uint_as_float((unsigned)hi << 16);
  float fl = f - fh;
  unsigned u2 = __float_as_uint(fl);
  unsigned r2 = u2 + 0x7FFFu + ((u2 >> 16) & 1u);
  lo = (unsigned short)(r2 >> 16);
}

// ---------------------------------------------------------------------------
// Twiddle table: twst[(1<<(s-1))-1 + j] = exp(-2*pi*i*j / (1<<s)), s = 1..12.
// ---------------------------------------------------------------------------
__global__ __launch_bounds__(256) void twiddle_init_kernel(float2* __restrict__ twst)
{
  int idx = blockIdx.x * 256 + threadIdx.x;
  if (idx >= 4095) return;
  int v  = idx + 1;
  int fl = 31 - __clz(v);          // v in [2^fl, 2^(fl+1))
  int j  = v - (1 << fl);
  int len = 1 << (fl + 1);
  double ang = -6.283185307179586476925286766559 * (double)j / (double)len;
  twst[idx] = make_float2((float)cos(ang), (float)sin(ang));
}

// ---------------------------------------------------------------------------
// 2048-point complex FFT in LDS. radix-2 DIT, bit-reversed input permutation,
// natural-order output. 256 threads, 4 butterflies/thread/stage.
// ---------------------------------------------------------------------------
__device__ __forceinline__ void fft2048_lds(float* re, float* im,
                                            const float2* twsl, int tid)
{
  for (int idx = tid; idx < 2048; idx += 256) {
    int r = (int)(__brev((unsigned)idx) >> 21);
    if (r > idx) {
      float a = re[idx]; re[idx] = re[r]; re[r] = a;
      float b = im[idx]; im[idx] = im[r]; im[r] = b;
    }
  }
  __syncthreads();
  for (int s = 1; s <= 11; s++) {
    int half = 1 << (s - 1);
    #pragma unroll
    for (int w = 0; w < 4; w++) {
      int bf = tid + (w << 8);
      int j  = bf & (half - 1);
      int g  = bf >> (s - 1);
      int p0 = (g << s) + j;
      int p1 = p0 + half;
      float2 tw = twsl[half - 1 + j];
      float xr = re[p1], xi = im[p1];
      float tr = xr * tw.x - xi * tw.y;
      float ti = xr * tw.y + xi * tw.x;
      float ur = re[p0], ui = im[p0];
      re[p0] = ur + tr; im[p0] = ui + ti;
      re[p1] = ur - tr; im[p1] = ui - ti;
    }
    __syncthreads();
  }
}

// ---------------------------------------------------------------------------
// Encoder (chunk): X[bc][h][l] = sum_d seq[bc][l][d]*encW[d][h] + encb[h]
// ---------------------------------------------------------------------------
__global__ __launch_bounds__(256) void encoder_kernel(
    const float* __restrict__ seq, const float* __restrict__ encW,
    const float* __restrict__ encb, float* __restrict__ X)
{
  int bid = blockIdx.x;
  int lt = bid & 7;
  int h  = (bid >> 3) & 511;
  int bc = bid >> 12;              // local chunk batch
  int l  = lt * 256 + threadIdx.x;
  const float* sp = seq + ((size_t)bc * kL + l) * 5;
  float acc = encb[h];
  #pragma unroll
  for (int d = 0; d < 5; d++) acc += sp[d] * encW[d * kH + h];
  X[((size_t)bc * kH + h) * kL + l] = acc;
}

// ---------------------------------------------------------------------------
// LN stats over H per (bc,l): mu, rstd. grid: CB*32; block 256 = 4 hg x 64 l
// ---------------------------------------------------------------------------
__global__ __launch_bounds__(256) void ln_stats_kernel(
    const float* __restrict__ X, float* __restrict__ mu, float* __restrict__ rstd)
{
  int b  = blockIdx.x >> 5;        // local chunk batch
  int l0 = (blockIdx.x & 31) * 64;
  int g  = threadIdx.x >> 6;
  int lt = threadIdx.x & 63;
  const float* xb = X + (size_t)b * kH * kL + l0 + lt;
  float s = 0.f, q = 0.f;
  for (int h = g; h < kH; h += 4) {
    float v = xb[(size_t)h * kL];
    s += v; q += v * v;
  }
  __shared__ float ss[4][64], qq[4][64];
  ss[g][lt] = s; qq[g][lt] = q;
  __syncthreads();
  if (threadIdx.x < 64) {
    float S = ss[0][threadIdx.x] + ss[1][threadIdx.x] + ss[2][threadIdx.x] + ss[3][threadIdx.x];
    float Q = qq[0][threadIdx.x] + qq[1][threadIdx.x] + qq[2][threadIdx.x] + qq[3][threadIdx.x];
    float m   = S * (1.f / kH);
    float var = Q * (1.f / kH) - m * m;
    mu[b * kL + l0 + threadIdx.x]   = m;
    rstd[b * kL + l0 + threadIdx.x] = 1.f / sqrtf(var + 1e-5f);
  }
}

// ---------------------------------------------------------------------------
// Per-(layer,h,n) SSM coefficients for ALL 4 layers at once.
// ---------------------------------------------------------------------------
__global__ __launch_bounds__(256) void coeff_kernel(
    const float* __restrict__ logst, const float* __restrict__ Are,
    const float* __restrict__ Aim, const float* __restrict__ Bre,
    const float* __restrict__ Bim, const float* __restrict__ Cp,
    float4* __restrict__ coeff)
{
  int idx = blockIdx.x * 256 + threadIdx.x;   // (layer*512 + h)*64 + n
  float dt = expf(logst[idx >> 6]);           // logst is [4][512] flat
  float ar = -expf(Are[idx]);
  float ai = Aim[idx];
  float wre = dt * ar, wim = dt * ai;
  float er  = expf(wre);
  float dAr = er * cosf(wim), dAi = er * sinf(wim);
  float numr = dAr - 1.f, numi = dAi;
  float den  = ar * ar + ai * ai;
  float qr = (numr * ar + numi * ai) / den;     // (dA-1)/A
  float qi = (numi * ar - numr * ai) / den;
  float br = Bre[idx], bi = Bim[idx];
  float tr = dt * (br * qr - bi * qi);          // dB
  float ti = dt * (br * qi + bi * qr);
  float cr = Cp[2 * idx], ci = Cp[2 * idx + 1];
  float ccr = 2.f * (cr * tr - ci * ti);        // 2*C*dB
  float cci = 2.f * (cr * ti + ci * tr);
  coeff[idx] = make_float4(wre, wim, ccr, cci);
}

// ---------------------------------------------------------------------------
// SSM kernel row k[l] = Re(sum_n cc*exp(w*l)), then half-spectrum of its
// length-4096 zero-padded rFFT. One block per grid row (layer*h or h).
// ---------------------------------------------------------------------------
__global__ __launch_bounds__(256) void kfft_kernel(
    const float4* __restrict__ coeff, const float2* __restrict__ twst,
    float2* __restrict__ Kf)
{
  __shared__ float sm[2048 * 2 + 2047 * 2];
  float* cre  = sm;
  float* cim  = sm + 2048;
  float2* twsl = (float2*)(sm + 4096);
  int tid = threadIdx.x;
  int row = blockIdx.x;
  for (int idx = tid; idx < 2047; idx += 256) twsl[idx] = twst[idx];
  float kreg[8] = {0.f, 0.f, 0.f, 0.f, 0.f, 0.f, 0.f, 0.f};
  const float4* ch = coeff + (size_t)row * kN;
  for (int n = 0; n < kN; n++) {
    float4 c = ch[n];
    #pragma unroll
    for (int i = 0; i < 8; i++) {
      float l = (float)(i * 256 + tid);
      float e = expf(c.x * l);
      float sn, cs;
      sincosf(c.y * l, &sn, &cs);
      kreg[i] += e * (c.z * cs - c.w * sn);
    }
  }
  // pack real k (zero-padded to 4096) into 2048 complex: c[j] = k[2j]+i*k[2j+1]
  #pragma unroll
  for (int i = 0; i < 8; i++) {
    int j = i * 128 + (tid >> 1);
    if (tid & 1) cim[j] = kreg[i]; else cre[j] = kreg[i];
  }
  for (int j = 1024 + tid; j < 2048; j += 256) { cre[j] = 0.f; cim[j] = 0.f; }
  __syncthreads();
  fft2048_lds(cre, cim, twsl, tid);
  // unpack: U[k] = Fe[k] + w4096^k * Fo[k]
  float2* kfh = Kf + (size_t)row * 2049;
  #pragma unroll
  for (int i = 0; i < 8; i++) {
    int k  = i * 256 + tid;
    int mk = (2048 - k) & 2047;
    float ar = cre[k], ai2 = cim[k], br = cre[mk], bi = cim[mk];
    float fer = 0.5f * (ar + br),  fei = 0.5f * (ai2 - bi);
    float fo_r = 0.5f * (ai2 + bi), foi = 0.5f * (br - ar);
    float2 w = twst[2047 + k];
    kfh[k] = make_float2(fer + w.x * fo_r - w.y * foi,
                         fei + w.x * foi + w.y * fo_r);
  }
  if (tid == 0) kfh[2048] = make_float2(cre[0] - cim[0], 0.f);
}

// ---------------------------------------------------------------------------
// Fused: inline LN apply -> rFFT(z) -> x Kf -> irFFT -> +D*z -> GELU -> Y
// one block per (bc,h) row. LDS: 48 KB
// ---------------------------------------------------------------------------
__global__ __launch_bounds__(256) void conv_kernel(
    const float* __restrict__ X, const float* __restrict__ mu,
    const float* __restrict__ rstd, const float* __restrict__ gam,
    const float* __restrict__ bet, const float* __restrict__ Dp,
    const float2* __restrict__ Kf, const float2* __restrict__ twst,
    float* __restrict__ Y)
{
  __shared__ float sm[12288];
  float* cre = sm;
  float* cim = sm + 2048;
  float* Ure = sm + 4096;   // 2049
  float* Uim = sm + 6145;   // 2049
  float2* twsl = (float2*)(sm + 8194);  // 2047 float2
  int tid = threadIdx.x;
  int bid = blockIdx.x;          // bc*512 + h
  int b = bid >> 9, h = bid & 511;
  for (int idx = tid; idx < 2047; idx += 256) twsl[idx] = twst[idx];
  const float* xrow  = X + (size_t)bid * kL;
  const float* murow = mu + b * kL;
  const float* rrow  = rstd + b * kL;
  float gam_h = gam[h], bet_h = bet[h], d_h = Dp[h];
  float zreg[8];
  #pragma unroll
  for (int i = 0; i < 8; i++) {
    int l = i * 256 + tid;
    zreg[i] = (xrow[l] - murow[l]) * rrow[l] * gam_h + bet_h;
  }
  // pack z (zero-padded to 4096)
  #pragma unroll
  for (int i = 0; i < 8; i++) {
    int j = i * 128 + (tid >> 1);
    if (tid & 1) cim[j] = zreg[i]; else cre[j] = zreg[i];
  }
  for (int j = 1024 + tid; j < 2048; j += 256) { cre[j] = 0.f; cim[j] = 0.f; }
  __syncthreads();
  fft2048_lds(cre, cim, twsl, tid);
  // unpack to half-spectrum U[0..2048]
  #pragma unroll
  for (int i = 0; i < 8; i++) {
    int k  = i * 256 + tid;
    int mk = (2048 - k) & 2047;
    float ar = cre[k], ai2 = cim[k], br = cre[mk], bi = cim[mk];
    float fer = 0.5f * (ar + br),  fei = 0.5f * (ai2 - bi);
    float fo_r = 0.5f * (ai2 + bi), foi = 0.5f * (br - ar);
    float2 w = twst[2047 + k];
    Ure[k] = fer + w.x * fo_r - w.y * foi;
    Uim[k] = fei + w.x * foi + w.y * fo_r;
  }
  if (tid == 0) { Ure[2048] = cre[0] - cim[0]; Uim[2048] = 0.f; }
  __syncthreads();
  // P = U*Kf ; repack C'[k] = E' + i O' ; store conj(C') for inverse-by-conj
  const float2* kfh = Kf + (size_t)h * 2049;
  #pragma unroll
  for (int i = 0; i < 8; i++) {
    int k  = i * 256 + tid;
    int mk = 2048 - k;
    float2 k1 = kfh[k], k2 = kfh[mk];
    float Ukr = Ure[k],  Uki = Uim[k];
    float Umr = Ure[mk], Umi = Uim[mk];
    float Pr = Ukr * k1.x - Uki * k1.y, Pi = Ukr * k1.y + Uki * k1.x;
    float Qr = Umr * k2.x - Umi * k2.y, Qi = Umr * k2.y + Umi * k2.x;
    float epr = 0.5f * (Pr + Qr), epi = 0.5f * (Pi - Qi);
    float dr  = 0.5f * (Pr - Qr), di  = 0.5f * (Pi + Qi);
    float2 w = twst[2047 + k];
    float opr = w.x * dr + w.y * di;     // w^{-k} * (..)
    float opi = w.x * di - w.y * dr;
    cre[k] = epr - opi;                  // Re C'
    cim[k] = -(epi + opr);               // -Im C'  (conj)
  }
  __syncthreads();
  fft2048_lds(cre, cim, twsl, tid);
  // y[2j] = Re/2048, y[2j+1] = -Im/2048 ; then skip D*z, exact GELU
  float* yrow = Y + (size_t)bid * kL;
  constexpr float inv = 1.f / 2048.f;
  #pragma unroll
  for (int i = 0; i < 8; i++) {
    int l = i * 256 + tid;
    int j = i * 128 + (tid >> 1);
    float v = (tid & 1) ? (-cim[j]) : cre[j];
    v = v * inv + d_h * zreg[i];
    yrow[l] = 0.5f * v * (1.f + erff(v * 0.70710678f));
  }
}

// ---------------------------------------------------------------------------
// W prep (all 4 layers once): Wt_hi/lo[m][k] = split(W[k][m]).  32x32 LDS tile.
// grid (16,16,4), block 256.
// ---------------------------------------------------------------------------
__global__ __launch_bounds__(256) void wprep_kernel(
    const float* __restrict__ W, short* __restrict__ WtHi, short* __restrict__ WtLo)
{
  __shared__ float t[32][33];
  int l = blockIdx.z, k0 = blockIdx.y * 32, m0 = blockIdx.x * 32;
  int c = threadIdx.x & 31, r0 = threadIdx.x >> 5;   // 8 rows per pass
  const float* wp = W + ((size_t)l * kH + k0) * kH + m0;
  #pragma unroll
  for (int it = 0; it < 4; ++it) {
    int r = r0 + it * 8;
    t[r][c] = wp[(size_t)r * kH + c];
  }
  __syncthreads();
  #pragma unroll
  for (int it = 0; it < 4; ++it) {
    int mr = r0 + it * 8;
    float v = t[c][mr];                 // = W[k0+c][m0+mr]
    unsigned short hi, lo;
    bf16_split(v, hi, lo);
    size_t oa = ((size_t)l * kH + m0 + mr) * kH + k0 + c;
    WtHi[oa] = (short)hi;
    WtLo[oa] = (short)lo;
  }
}

// ---------------------------------------------------------------------------
// Y transpose+split: Yt_hi/lo[b][n][k] = split(Y[b][k][n]). 64x64 LDS tile.
// grid (kL/64, kH/64, CB), block 256.
// ---------------------------------------------------------------------------
__global__ __launch_bounds__(256) void ytrans_kernel(
    const float* __restrict__ Y, short* __restrict__ YtHi, short* __restrict__ YtLo)
{
  __shared__ float t[64][65];
  int b = blockIdx.z, k0 = blockIdx.y * 64, n0 = blockIdx.x * 64;
  int c = threadIdx.x & 63, r0 = threadIdx.x >> 6;   // 4 rows per pass
  const float* yp = Y + ((size_t)b * kH + k0) * kL + n0;
  #pragma unroll
  for (int it = 0; it < 16; ++it) {
    int r = r0 + it * 4;
    t[r][c] = yp[(size_t)r * kL + c];
  }
  __syncthreads();
  #pragma unroll
  for (int it = 0; it < 16; ++it) {
    int nr = r0 + it * 4;
    float v = t[c][nr];                 // = Y[b][k0+c][n0+nr]
    unsigned short hi, lo;
    bf16_split(v, hi, lo);
    size_t oa = ((size_t)b * kL + n0 + nr) * kH + k0 + c;
    YtHi[oa] = (short)hi;
    YtLo[oa] = (short)lo;
  }
}

// ---------------------------------------------------------------------------
// MFMA GEMM: X[b][m][n] += bias[m] + sum_k W[k][m]*Y[b][k][n]
// A = Wt (m x k, k-contig), B = Yt (n x k, k-contig), both bf16 hi/lo planes.
// 3-product split: Ah*Bh + Ah*Bl + Al*Bh (error ~2^-18).
// Tile 128(m) x 128(n), BK=32, 4 waves of 64x64, v_mfma_f32_16x16x32_bf16.
// Fragment layouts (verified, learn_hip m89):
//   A: lane holds A[lane%16][(lane/16)*8 + j], j=0..7
//   B: lane holds B[(lane/16)*8 + j][lane%16]
//   D: lane holds D[(lane/16)*4 + r][lane%16]
// grid (4 m-tiles, kL/128 n-tiles, CB), block 256.
// ---------------------------------------------------------------------------
__global__ __launch_bounds__(256) void gemm_mfma_kernel(
    const short* __restrict__ WtHi, const short* __restrict__ WtLo,
    const short* __restrict__ YtHi, const short* __restrict__ YtLo,
    const float* __restrict__ bias, float* __restrict__ X)
{
  __shared__ __align__(16) short AsHi[128 * 32];
  __shared__ __align__(16) short AsLo[128 * 32];
  __shared__ __align__(16) short BsHi[128 * 32];
  __shared__ __align__(16) short BsLo[128 * 32];
  const int tid = threadIdx.x;
  const int b  = blockIdx.z;
  const int m0 = blockIdx.x * 128;
  const int n0 = blockIdx.y * 128;
  const int lane = tid & 63, w = tid >> 6;
  const int wr = w >> 1, wc = w & 1;
  const int lr = lane & 15, lk = (lane >> 4) * 8;

  f32x4 acc[4][4];
  #pragma unroll
  for (int i = 0; i < 4; ++i)
    #pragma unroll
    for (int j = 0; j < 4; ++j)
      #pragma unroll
      for (int r = 0; r < 4; ++r) acc[i][j][r] = 0.f;

  const size_t abase = (size_t)m0 * kH;
  const size_t bbase = ((size_t)b * kL + n0) * kH;

  for (int k0 = 0; k0 < kH; k0 += 32) {
    // stage: 128 rows x 32 k, chunks c = tid + p*256; row = c>>2, ko = (c&3)*8
    #pragma unroll
    for (int p = 0; p < 2; ++p) {
      int c = tid + p * 256;
      int rr = c >> 2, ko = (c & 3) * 8;
      size_t ga = abase + (size_t)rr * kH + k0 + ko;
      *(s16x8*)&AsHi[rr * 32 + ko] = *(const s16x8*)&WtHi[ga];
      *(s16x8*)&AsLo[rr * 32 + ko] = *(const s16x8*)&WtLo[ga];
      size_t gb = bbase + (size_t)rr * kH + k0 + ko;
      *(s16x8*)&BsHi[rr * 32 + ko] = *(const s16x8*)&YtHi[gb];
      *(s16x8*)&BsLo[rr * 32 + ko] = *(const s16x8*)&YtLo[gb];
    }
    __syncthreads();
    s16x8 ah[4], al[4], bh[4], bl[4];
    #pragma unroll
    for (int f = 0; f < 4; ++f) {
      int ra = (wr * 64 + f * 16 + lr) * 32 + lk;
      ah[f] = *(const s16x8*)&AsHi[ra];
      al[f] = *(const s16x8*)&AsLo[ra];
      int rb = (wc * 64 + f * 16 + lr) * 32 + lk;
      bh[f] = *(const s16x8*)&BsHi[rb];
      bl[f] = *(const s16x8*)&BsLo[rb];
    }
    #pragma unroll
    for (int i = 0; i < 4; ++i)
      #pragma unroll
      for (int j = 0; j < 4; ++j) {
        acc[i][j] = __builtin_amdgcn_mfma_f32_16x16x32_bf16(ah[i], bh[j], acc[i][j], 0, 0, 0);
        acc[i][j] = __builtin_amdgcn_mfma_f32_16x16x32_bf16(ah[i], bl[j], acc[i][j], 0, 0, 0);
        acc[i][j] = __builtin_amdgcn_mfma_f32_16x16x32_bf16(al[i], bh[j], acc[i][j], 0, 0, 0);
      }
    __syncthreads();
  }
  // epilogue: residual add into X
  #pragma unroll
  for (int i = 0; i < 4; ++i) {
    int m = m0 + wr * 64 + i * 16 + (lane >> 4) * 4;
    #pragma unroll
    for (int j = 0; j < 4; ++j) {
      int n = n0 + wc * 64 + j * 16 + lr;
      #pragma unroll
      for (int r = 0; r < 4; ++r) {
        float* xp = &X[((size_t)b * kH + m + r) * kL + n];
        *xp += acc[i][j][r] + bias[m + r];
      }
    }
  }
}

// ---------------------------------------------------------------------------
// pooled[row] = mean_l X[row][l]
// ---------------------------------------------------------------------------
__global__ __launch_bounds__(256) void pool_kernel(const float* __restrict__ X,
                                                   float* __restrict__ pooled)
{
  int bid = blockIdx.x;
  const float* row = X + (size_t)bid * kL;
  float s = 0.f;
  for (int i = threadIdx.x; i < kL; i += 256) s += row[i];
  for (int off = 32; off > 0; off >>= 1) s += __shfl_down(s, off);
  __shared__ float p[4];
  if ((threadIdx.x & 63) == 0) p[threadIdx.x >> 6] = s;
  __syncthreads();
  if (threadIdx.x == 0) pooled[bid] = (p[0] + p[1] + p[2] + p[3]) * (1.f / kL);
}

// ---------------------------------------------------------------------------
// fusion MLP + two heads. one block per b (full batch).
// ---------------------------------------------------------------------------
__global__ __launch_bounds__(256) void head_kernel(
    const float* __restrict__ pooled, const int* __restrict__ com,
    const int* __restrict__ cou, const float* __restrict__ comE,
    const float* __restrict__ couE, const float* __restrict__ fusW,
    const float* __restrict__ fusb, const float* __restrict__ vW1,
    const float* __restrict__ vb1, const float* __restrict__ vW2,
    const float* __restrict__ vb2, const float* __restrict__ wW1,
    const float* __restrict__ wb1, const float* __restrict__ wW2,
    const float* __restrict__ wb2, float* __restrict__ out)
{
  __shared__ float feat[768];
  __shared__ float h1[512];
  __shared__ float vv[256];
  int tid = threadIdx.x;
  int b = blockIdx.x;
  int cid = com[b], ct = cou[b];
  for (int i = tid; i < 512; i += 256) feat[i] = pooled[b * kH + i];
  if (tid < 128) {
    feat[512 + tid] = comE[cid * 128 + tid];
    feat[640 + tid] = couE[ct * 128 + tid];
  }
  __syncthreads();
  #pragma unroll
  for (int jj = 0; jj < 2; jj++) {
    int j = tid + jj * 256;
    float acc = fusb[j];
    for (int i = 0; i < 768; i++) acc += feat[i] * fusW[i * kH + j];
    h1[j] = acc;
  }
  __syncthreads();
  {
    float acc = vb1[tid];
    for (int i = 0; i < 512; i++) acc += h1[i] * vW1[i * 256 + tid];
    vv[tid] = fmaxf(acc, 0.f) * vW2[tid];
  }
  __syncthreads();
  for (int s = 128; s > 0; s >>= 1) {
    if (tid < s) vv[tid] += vv[tid + s];
    __syncthreads();
  }
  if (tid == 0) out[b * 2 + 0] = vv[0] + vb2[0];
  __syncthreads();
  {
    float acc = wb1[tid];
    for (int i = 0; i < 512; i++) acc += h1[i] * wW1[i * 256 + tid];
    vv[tid] = fmaxf(acc, 0.f) * wW2[tid];
  }
  __syncthreads();
  for (int s = 128; s > 0; s >>= 1) {
    if (tid < s) vv[tid] += vv[tid + s];
    __syncthreads();
  }
  if (tid == 0) out[b * 2 + 1] = vv[0] + wb2[0];
}

}  // namespace

extern "C" void kernel_launch(void* const* d_in, const int* in_sizes, int n_in,
                              void* d_out, int out_size, void* d_ws, size_t ws_size,
                              hipStream_t stream)
{
  (void)in_sizes; (void)n_in; (void)out_size;
  const float* seq   = (const float*)d_in[0];
  const int*   com   = (const int*)d_in[1];
  const int*   cou   = (const int*)d_in[2];
  const float* encW  = (const float*)d_in[3];
  const float* encb  = (const float*)d_in[4];
  const float* comE  = (const float*)d_in[5];
  const float* couE  = (const float*)d_in[6];
  const float* logst = (const float*)d_in[7];
  const float* Ar    = (const float*)d_in[8];
  const float* Ai    = (const float*)d_in[9];
  const float* Br    = (const float*)d_in[10];
  const float* Bi    = (const float*)d_in[11];
  const float* Cp    = (const float*)d_in[12];
  const float* Dp    = (const float*)d_in[13];
  const float* outW  = (const float*)d_in[14];
  const float* outb  = (const float*)d_in[15];
  const float* lng   = (const float*)d_in[16];
  const float* lnb   = (const float*)d_in[17];
  const float* fusW  = (const float*)d_in[18];
  const float* fusb  = (const float*)d_in[19];
  const float* vW1   = (const float*)d_in[20];
  const float* vb1   = (const float*)d_in[21];
  const float* vW2   = (const float*)d_in[22];
  const float* vb2   = (const float*)d_in[23];
  const float* wW1   = (const float*)d_in[24];
  const float* wb1   = (const float*)d_in[25];
  const float* wW2   = (const float*)d_in[26];
  const float* wb2   = (const float*)d_in[27];
  float* out = (float*)d_out;

  // ---- adaptive workspace sizing (in floats) ----
  const size_t F_KF1   = (size_t)kH * 2049 * 2;       // one layer's spectrum
  const size_t F_COEFF = (size_t)4 * kH * kN * 4;     // all-layer coeffs
  const size_t F_TW    = 8192;
  const size_t F_POOL  = (size_t)kB * kH;
  const size_t F_WT    = (size_t)4 * kH * kH;         // 2 bf16 planes, 4 layers
  size_t nws = ws_size / sizeof(float);
  auto need = [&](size_t cb, bool kfall) -> size_t {
    return (kfall ? 4 : 1) * F_KF1 + F_COEFF + F_TW + F_POOL + F_WT
         + 2 * cb * (size_t)kL              // mu + rstd
         + 2 * cb * (size_t)kH * kL         // X + Y (fp32)
         + cb * (size_t)kH * kL;            // Yt hi+lo (bf16 planes)
  };
  const int cand[7] = {64, 32, 16, 8, 4, 2, 1};
  int CB = 0; bool kfAll = true;
  for (int i = 0; i < 7 && !CB; i++)
    if (need(cand[i], true) <= nws) { CB = cand[i]; kfAll = true; }
  for (int i = 0; i < 7 && !CB; i++)
    if (need(cand[i], false) <= nws) { CB = cand[i]; kfAll = false; }
  if (!CB) { CB = 1; kfAll = false; }

  float* ws = (float*)d_ws;
  size_t o = 0;
  float2* Kf    = (float2*)(ws + o); o += (kfAll ? 4 : 1) * F_KF1;
  float4* coeff = (float4*)(ws + o); o += F_COEFF;
  float2* twst  = (float2*)(ws + o); o += F_TW;
  float*  pooled= ws + o;            o += F_POOL;
  short*  WtHi  = (short*)(ws + o);  o += F_WT / 2;
  short*  WtLo  = (short*)(ws + o);  o += F_WT / 2;
  float*  mu    = ws + o;            o += (size_t)CB * kL;
  float*  rstd  = ws + o;            o += (size_t)CB * kL;
  float*  X     = ws + o;            o += (size_t)CB * kH * kL;
  float*  Yb    = ws + o;            o += (size_t)CB * kH * kL;
  short*  YtHi  = (short*)(ws + o);  o += (size_t)CB * kH * kL / 2;
  short*  YtLo  = (short*)(ws + o);  o += (size_t)CB * kH * kL / 2;

  twiddle_init_kernel<<<16, 256, 0, stream>>>(twst);
  coeff_kernel<<<512, 256, 0, stream>>>(logst, Ar, Ai, Br, Bi, Cp, coeff);
  wprep_kernel<<<dim3(16, 16, 4), 256, 0, stream>>>(outW, WtHi, WtLo);
  if (kfAll) kfft_kernel<<<4 * kH, 256, 0, stream>>>(coeff, twst, Kf);

  const int nchunk = kB / CB;
  for (int c = 0; c < nchunk; c++) {
    const int b0 = c * CB;
    encoder_kernel<<<CB * kH * (kL / 256), 256, 0, stream>>>(
        seq + (size_t)b0 * kL * 5, encW, encb, X);
    for (int layer = 0; layer < 4; layer++) {
      if (!kfAll)
        kfft_kernel<<<kH, 256, 0, stream>>>(
            coeff + (size_t)layer * kH * kN, twst, Kf);
      ln_stats_kernel<<<CB * (kL / 64), 256, 0, stream>>>(X, mu, rstd);
      conv_kernel<<<CB * kH, 256, 0, stream>>>(
          X, mu, rstd, lng + layer * kH, lnb + layer * kH, Dp + layer * kH,
          kfAll ? Kf + (size_t)layer * kH * 2049 : Kf, twst, Yb);
      ytrans_kernel<<<dim3(kL / 64, kH / 64, CB), 256, 0, stream>>>(Yb, YtHi, YtLo);
      gemm_mfma_kernel<<<dim3(4, kL / 128, CB), 256, 0, stream>>>(
          WtHi + (size_t)layer * kH * kH, WtLo + (size_t)layer * kH * kH,
          YtHi, YtLo, outb + layer * kH, X);
    }
    pool_kernel<<<CB * kH, 256, 0, stream>>>(X, pooled + (size_t)b0 * kH);
  }

  head_kernel<<<kB, 256, 0, stream>>>(pooled, com, cou, comE, couE, fusW, fusb,
                                      vW1, vb1, vW2, vb2, wW1, wb1, wW2, wb2, out);
}

// Round 8
// 6825.647 us; speedup vs baseline: 1.3997x; 1.1266x over previous
//
#include <hip/hip_runtime.h>
#include <cmath>

namespace {

constexpr int kB = 64;
constexpr int kL = 2048;
constexpr int kH = 512;
constexpr int kN = 64;

typedef short s16x8 __attribute__((ext_vector_type(8)));
typedef float f32x4 __attribute__((ext_vector_type(4)));

// bf16 round-to-nearest-even split: f ~= hi + lo (both bf16)
__device__ __forceinline__ void bf16_split(float f, unsigned short& hi, unsigned short& lo)
{
  unsigned u = __float_as_uint(f);
  unsigned rh = u + 0x7FFFu + ((u >> 16) & 1u);
  hi = (unsigned short)(rh >> 16);
  float fh = __uint_as_float((unsigned)hi << 16);
  float fl = f - fh;
  unsigned u2 = __float_as_uint(fl);
  unsigned r2 = u2 + 0x7FFFu + ((u2 >> 16) & 1u);
  lo = (unsigned short)(r2 >> 16);
}

// ---------------------------------------------------------------------------
// Twiddle table: twst[(1<<(s-1))-1 + j] = exp(-2*pi*i*j / (1<<s)), s = 1..12.
// ---------------------------------------------------------------------------
__global__ __launch_bounds__(256) void twiddle_init_kernel(float2* __restrict__ twst)
{
  int idx = blockIdx.x * 256 + threadIdx.x;
  if (idx >= 4095) return;
  int v  = idx + 1;
  int fl = 31 - __clz(v);          // v in [2^fl, 2^(fl+1))
  int j  = v - (1 << fl);
  int len = 1 << (fl + 1);
  double ang = -6.283185307179586476925286766559 * (double)j / (double)len;
  twst[idx] = make_float2((float)cos(ang), (float)sin(ang));
}

// ---------------------------------------------------------------------------
// 2048-point complex FFT in LDS. Radix-4 passes (pairs of radix-2 DIT stages
// composed; twiddles from the same table: w1 = tw[h-1+j], w2 = tw[2h-1+j],
// upper-half level-(s+1) twiddle = -i*w2). Bit-reversed input permutation,
// natural-order output. 5 radix-4 passes (s=1,3,5,7,9) + final radix-2 (s=11).
// 256 threads: 2 quads/thread/pass, 4 bf/thread final stage.
// ---------------------------------------------------------------------------
__device__ __forceinline__ void fft2048_lds(float* re, float* im,
                                            const float2* twsl, int tid)
{
  for (int idx = tid; idx < 2048; idx += 256) {
    int r = (int)(__brev((unsigned)idx) >> 21);
    if (r > idx) {
      float a = re[idx]; re[idx] = re[r]; re[r] = a;
      float b = im[idx]; im[idx] = im[r]; im[r] = b;
    }
  }
  __syncthreads();
  #pragma unroll
  for (int s = 1; s <= 9; s += 2) {
    const int h = 1 << (s - 1);
    #pragma unroll
    for (int u = 0; u < 2; ++u) {
      const int q = tid + (u << 8);          // quad index in [0,512)
      if (s == 1) {
        // h=1, j=0, w1=w2=1; contiguous quad -> float4 fast path
        const int p = q << 2;
        float4 xr = *(const float4*)&re[p];
        float4 xi = *(const float4*)&im[p];
        float u0r = xr.x + xr.y, u0i = xi.x + xi.y;
        float u1r = xr.x - xr.y, u1i = xi.x - xi.y;
        float u2r = xr.z + xr.w, u2i = xi.z + xi.w;
        float u3r = xr.z - xr.w, u3i = xi.z - xi.w;
        float4 orr, oii;
        orr.x = u0r + u2r; oii.x = u0i + u2i;
        orr.z = u0r - u2r; oii.z = u0i - u2i;
        orr.y = u1r + u3i; oii.y = u1i - u3r;   // u1 + (-i)*u3
        orr.w = u1r - u3i; oii.w = u1i + u3r;   // u1 - (-i)*u3
        *(float4*)&re[p] = orr;
        *(float4*)&im[p] = oii;
      } else {
        const int j = q & (h - 1);
        const int G = q >> (s - 1);
        const int p = (G << (s + 1)) + j;
        float x0r = re[p],         x0i = im[p];
        float x1r = re[p + h],     x1i = im[p + h];
        float x2r = re[p + 2 * h], x2i = im[p + 2 * h];
        float x3r = re[p + 3 * h], x3i = im[p + 3 * h];
        float2 w1 = twsl[h - 1 + j];
        float2 w2 = twsl[2 * h - 1 + j];
        // stage s (both radix-2 butterflies share w1)
        float t1r = x1r * w1.x - x1i * w1.y, t1i = x1r * w1.y + x1i * w1.x;
        float t3r = x3r * w1.x - x3i * w1.y, t3i = x3r * w1.y + x3i * w1.x;
        float u0r = x0r + t1r, u0i = x0i + t1i;
        float u1r = x0r - t1r, u1i = x0i - t1i;
        float u2r = x2r + t3r, u2i = x2i + t3i;
        float u3r = x2r - t3r, u3i = x2i - t3i;
        // stage s+1: pair (p, p+2h) uses w2; pair (p+h, p+3h) uses -i*w2
        float m0r = u2r * w2.x - u2i * w2.y, m0i = u2r * w2.y + u2i * w2.x;
        float m1r = u3r * w2.x - u3i * w2.y, m1i = u3r * w2.y + u3i * w2.x;
        re[p]         = u0r + m0r; im[p]         = u0i + m0i;
        re[p + 2 * h] = u0r - m0r; im[p + 2 * h] = u0i - m0i;
        re[p + h]     = u1r + m1i; im[p + h]     = u1i - m1r;
        re[p + 3 * h] = u1r - m1i; im[p + 3 * h] = u1i + m1r;
      }
    }
    __syncthreads();
  }
  // final radix-2 stage s=11 (half=1024, g=0, j=bf)
  #pragma unroll
  for (int w = 0; w < 4; ++w) {
    int j  = tid + (w << 8);
    int p1 = j + 1024;
    float2 tw = twsl[1023 + j];
    float xr = re[p1], xi = im[p1];
    float tr = xr * tw.x - xi * tw.y;
    float ti = xr * tw.y + xi * tw.x;
    float ur = re[j], ui = im[j];
    re[j]  = ur + tr; im[j]  = ui + ti;
    re[p1] = ur - tr; im[p1] = ui - ti;
  }
  __syncthreads();
}

// ---------------------------------------------------------------------------
// Encoder (chunk): X[bc][h][l] = sum_d seq[bc][l][d]*encW[d][h] + encb[h]
// ---------------------------------------------------------------------------
__global__ __launch_bounds__(256) void encoder_kernel(
    const float* __restrict__ seq, const float* __restrict__ encW,
    const float* __restrict__ encb, float* __restrict__ X)
{
  int bid = blockIdx.x;
  int lt = bid & 7;
  int h  = (bid >> 3) & 511;
  int bc = bid >> 12;              // local chunk batch
  int l  = lt * 256 + threadIdx.x;
  const float* sp = seq + ((size_t)bc * kL + l) * 5;
  float acc = encb[h];
  #pragma unroll
  for (int d = 0; d < 5; d++) acc += sp[d] * encW[d * kH + h];
  X[((size_t)bc * kH + h) * kL + l] = acc;
}

// ---------------------------------------------------------------------------
// LN stats over H per (bc,l): mu, rstd. grid: CB*32; block 256 = 4 hg x 64 l
// ---------------------------------------------------------------------------
__global__ __launch_bounds__(256) void ln_stats_kernel(
    const float* __restrict__ X, float* __restrict__ mu, float* __restrict__ rstd)
{
  int b  = blockIdx.x >> 5;        // local chunk batch
  int l0 = (blockIdx.x & 31) * 64;
  int g  = threadIdx.x >> 6;
  int lt = threadIdx.x & 63;
  const float* xb = X + (size_t)b * kH * kL + l0 + lt;
  float s = 0.f, q = 0.f;
  for (int h = g; h < kH; h += 4) {
    float v = xb[(size_t)h * kL];
    s += v; q += v * v;
  }
  __shared__ float ss[4][64], qq[4][64];
  ss[g][lt] = s; qq[g][lt] = q;
  __syncthreads();
  if (threadIdx.x < 64) {
    float S = ss[0][threadIdx.x] + ss[1][threadIdx.x] + ss[2][threadIdx.x] + ss[3][threadIdx.x];
    float Q = qq[0][threadIdx.x] + qq[1][threadIdx.x] + qq[2][threadIdx.x] + qq[3][threadIdx.x];
    float m   = S * (1.f / kH);
    float var = Q * (1.f / kH) - m * m;
    mu[b * kL + l0 + threadIdx.x]   = m;
    rstd[b * kL + l0 + threadIdx.x] = 1.f / sqrtf(var + 1e-5f);
  }
}

// ---------------------------------------------------------------------------
// Per-(layer,h,n) SSM coefficients for ALL 4 layers at once.
// ---------------------------------------------------------------------------
__global__ __launch_bounds__(256) void coeff_kernel(
    const float* __restrict__ logst, const float* __restrict__ Are,
    const float* __restrict__ Aim, const float* __restrict__ Bre,
    const float* __restrict__ Bim, const float* __restrict__ Cp,
    float4* __restrict__ coeff)
{
  int idx = blockIdx.x * 256 + threadIdx.x;   // (layer*512 + h)*64 + n
  float dt = expf(logst[idx >> 6]);           // logst is [4][512] flat
  float ar = -expf(Are[idx]);
  float ai = Aim[idx];
  float wre = dt * ar, wim = dt * ai;
  float er  = expf(wre);
  float dAr = er * cosf(wim), dAi = er * sinf(wim);
  float numr = dAr - 1.f, numi = dAi;
  float den  = ar * ar + ai * ai;
  float qr = (numr * ar + numi * ai) / den;     // (dA-1)/A
  float qi = (numi * ar - numr * ai) / den;
  float br = Bre[idx], bi = Bim[idx];
  float tr = dt * (br * qr - bi * qi);          // dB
  float ti = dt * (br * qi + bi * qr);
  float cr = Cp[2 * idx], ci = Cp[2 * idx + 1];
  float ccr = 2.f * (cr * tr - ci * ti);        // 2*C*dB
  float cci = 2.f * (cr * ti + ci * tr);
  coeff[idx] = make_float4(wre, wim, ccr, cci);
}

// ---------------------------------------------------------------------------
// SSM kernel row k[l] = Re(sum_n cc*exp(w*l)), then half-spectrum of its
// length-4096 zero-padded rFFT. One block per grid row (layer*h or h).
// ---------------------------------------------------------------------------
__global__ __launch_bounds__(256) void kfft_kernel(
    const float4* __restrict__ coeff, const float2* __restrict__ twst,
    float2* __restrict__ Kf)
{
  __shared__ float sm[2048 * 2 + 2047 * 2];
  float* cre  = sm;
  float* cim  = sm + 2048;
  float2* twsl = (float2*)(sm + 4096);
  int tid = threadIdx.x;
  int row = blockIdx.x;
  for (int idx = tid; idx < 2047; idx += 256) twsl[idx] = twst[idx];
  float kreg[8] = {0.f, 0.f, 0.f, 0.f, 0.f, 0.f, 0.f, 0.f};
  const float4* ch = coeff + (size_t)row * kN;
  for (int n = 0; n < kN; n++) {
    float4 c = ch[n];
    #pragma unroll
    for (int i = 0; i < 8; i++) {
      float l = (float)(i * 256 + tid);
      float e = expf(c.x * l);
      float sn, cs;
      sincosf(c.y * l, &sn, &cs);
      kreg[i] += e * (c.z * cs - c.w * sn);
    }
  }
  // pack real k (zero-padded to 4096) into 2048 complex: c[j] = k[2j]+i*k[2j+1]
  #pragma unroll
  for (int i = 0; i < 8; i++) {
    int j = i * 128 + (tid >> 1);
    if (tid & 1) cim[j] = kreg[i]; else cre[j] = kreg[i];
  }
  for (int j = 1024 + tid; j < 2048; j += 256) { cre[j] = 0.f; cim[j] = 0.f; }
  __syncthreads();
  fft2048_lds(cre, cim, twsl, tid);
  // unpack: U[k] = Fe[k] + w4096^k * Fo[k]
  float2* kfh = Kf + (size_t)row * 2049;
  #pragma unroll
  for (int i = 0; i < 8; i++) {
    int k  = i * 256 + tid;
    int mk = (2048 - k) & 2047;
    float ar = cre[k], ai2 = cim[k], br = cre[mk], bi = cim[mk];
    float fer = 0.5f * (ar + br),  fei = 0.5f * (ai2 - bi);
    float fo_r = 0.5f * (ai2 + bi), foi = 0.5f * (br - ar);
    float2 w = twst[2047 + k];
    kfh[k] = make_float2(fer + w.x * fo_r - w.y * foi,
                         fei + w.x * foi + w.y * fo_r);
  }
  if (tid == 0) kfh[2048] = make_float2(cre[0] - cim[0], 0.f);
}

// ---------------------------------------------------------------------------
// Fused: inline LN apply -> rFFT(z) -> x Kf -> irFFT -> +D*z -> GELU -> Y
// one block per (bc,h) row. LDS: 48 KB
// ---------------------------------------------------------------------------
__global__ __launch_bounds__(256) void conv_kernel(
    const float* __restrict__ X, const float* __restrict__ mu,
    const float* __restrict__ rstd, const float* __restrict__ gam,
    const float* __restrict__ bet, const float* __restrict__ Dp,
    const float2* __restrict__ Kf, const float2* __restrict__ twst,
    float* __restrict__ Y)
{
  __shared__ float sm[12288];
  float* cre = sm;
  float* cim = sm + 2048;
  float* Ure = sm + 4096;   // 2049
  float* Uim = sm + 6145;   // 2049
  float2* twsl = (float2*)(sm + 8194);  // 2047 float2
  int tid = threadIdx.x;
  int bid = blockIdx.x;          // bc*512 + h
  int b = bid >> 9, h = bid & 511;
  for (int idx = tid; idx < 2047; idx += 256) twsl[idx] = twst[idx];
  const float* xrow  = X + (size_t)bid * kL;
  const float* murow = mu + b * kL;
  const float* rrow  = rstd + b * kL;
  float gam_h = gam[h], bet_h = bet[h], d_h = Dp[h];
  float zreg[8];
  #pragma unroll
  for (int i = 0; i < 8; i++) {
    int l = i * 256 + tid;
    zreg[i] = (xrow[l] - murow[l]) * rrow[l] * gam_h + bet_h;
  }
  // pack z (zero-padded to 4096)
  #pragma unroll
  for (int i = 0; i < 8; i++) {
    int j = i * 128 + (tid >> 1);
    if (tid & 1) cim[j] = zreg[i]; else cre[j] = zreg[i];
  }
  for (int j = 1024 + tid; j < 2048; j += 256) { cre[j] = 0.f; cim[j] = 0.f; }
  __syncthreads();
  fft2048_lds(cre, cim, twsl, tid);
  // unpack to half-spectrum U[0..2048]
  #pragma unroll
  for (int i = 0; i < 8; i++) {
    int k  = i * 256 + tid;
    int mk = (2048 - k) & 2047;
    float ar = cre[k], ai2 = cim[k], br = cre[mk], bi = cim[mk];
    float fer = 0.5f * (ar + br),  fei = 0.5f * (ai2 - bi);
    float fo_r = 0.5f * (ai2 + bi), foi = 0.5f * (br - ar);
    float2 w = twst[2047 + k];
    Ure[k] = fer + w.x * fo_r - w.y * foi;
    Uim[k] = fei + w.x * foi + w.y * fo_r;
  }
  if (tid == 0) { Ure[2048] = cre[0] - cim[0]; Uim[2048] = 0.f; }
  __syncthreads();
  // P = U*Kf ; repack C'[k] = E' + i O' ; store conj(C') for inverse-by-conj
  const float2* kfh = Kf + (size_t)h * 2049;
  #pragma unroll
  for (int i = 0; i < 8; i++) {
    int k  = i * 256 + tid;
    int mk = 2048 - k;
    float2 k1 = kfh[k], k2 = kfh[mk];
    float Ukr = Ure[k],  Uki = Uim[k];
    float Umr = Ure[mk], Umi = Uim[mk];
    float Pr = Ukr * k1.x - Uki * k1.y, Pi = Ukr * k1.y + Uki * k1.x;
    float Qr = Umr * k2.x - Umi * k2.y, Qi = Umr * k2.y + Umi * k2.x;
    float epr = 0.5f * (Pr + Qr), epi = 0.5f * (Pi - Qi);
    float dr  = 0.5f * (Pr - Qr), di  = 0.5f * (Pi + Qi);
    float2 w = twst[2047 + k];
    float opr = w.x * dr + w.y * di;     // w^{-k} * (..)
    float opi = w.x * di - w.y * dr;
    cre[k] = epr - opi;                  // Re C'
    cim[k] = -(epi + opr);               // -Im C'  (conj)
  }
  __syncthreads();
  fft2048_lds(cre, cim, twsl, tid);
  // y[2j] = Re/2048, y[2j+1] = -Im/2048 ; then skip D*z, exact GELU
  float* yrow = Y + (size_t)bid * kL;
  constexpr float inv = 1.f / 2048.f;
  #pragma unroll
  for (int i = 0; i < 8; i++) {
    int l = i * 256 + tid;
    int j = i * 128 + (tid >> 1);
    float v = (tid & 1) ? (-cim[j]) : cre[j];
    v = v * inv + d_h * zreg[i];
    yrow[l] = 0.5f * v * (1.f + erff(v * 0.70710678f));
  }
}

// ---------------------------------------------------------------------------
// W prep (all 4 layers once): Wt_hi/lo[m][k] = split(W[k][m]).  32x32 LDS tile.
// grid (16,16,4), block 256.
// ---------------------------------------------------------------------------
__global__ __launch_bounds__(256) void wprep_kernel(
    const float* __restrict__ W, short* __restrict__ WtHi, short* __restrict__ WtLo)
{
  __shared__ float t[32][33];
  int l = blockIdx.z, k0 = blockIdx.y * 32, m0 = blockIdx.x * 32;
  int c = threadIdx.x & 31, r0 = threadIdx.x >> 5;   // 8 rows per pass
  const float* wp = W + ((size_t)l * kH + k0) * kH + m0;
  #pragma unroll
  for (int it = 0; it < 4; ++it) {
    int r = r0 + it * 8;
    t[r][c] = wp[(size_t)r * kH + c];
  }
  __syncthreads();
  #pragma unroll
  for (int it = 0; it < 4; ++it) {
    int mr = r0 + it * 8;
    float v = t[c][mr];                 // = W[k0+c][m0+mr]
    unsigned short hi, lo;
    bf16_split(v, hi, lo);
    size_t oa = ((size_t)l * kH + m0 + mr) * kH + k0 + c;
    WtHi[oa] = (short)hi;
    WtLo[oa] = (short)lo;
  }
}

// ---------------------------------------------------------------------------
// Y transpose+split: Yt_hi/lo[b][n][k] = split(Y[b][k][n]). 64x64 LDS tile.
// grid (kL/64, kH/64, CB), block 256.
// ---------------------------------------------------------------------------
__global__ __launch_bounds__(256) void ytrans_kernel(
    const float* __restrict__ Y, short* __restrict__ YtHi, short* __restrict__ YtLo)
{
  __shared__ float t[64][65];
  int b = blockIdx.z, k0 = blockIdx.y * 64, n0 = blockIdx.x * 64;
  int c = threadIdx.x & 63, r0 = threadIdx.x >> 6;   // 4 rows per pass
  const float* yp = Y + ((size_t)b * kH + k0) * kL + n0;
  #pragma unroll
  for (int it = 0; it < 16; ++it) {
    int r = r0 + it * 4;
    t[r][c] = yp[(size_t)r * kL + c];
  }
  __syncthreads();
  #pragma unroll
  for (int it = 0; it < 16; ++it) {
    int nr = r0 + it * 4;
    float v = t[c][nr];                 // = Y[b][k0+c][n0+nr]
    unsigned short hi, lo;
    bf16_split(v, hi, lo);
    size_t oa = ((size_t)b * kL + n0 + nr) * kH + k0 + c;
    YtHi[oa] = (short)hi;
    YtLo[oa] = (short)lo;
  }
}

// ---------------------------------------------------------------------------
// MFMA GEMM: X[b][m][n] += bias[m] + sum_k W[k][m]*Y[b][k][n]
// A = Wt (m x k, k-contig), B = Yt (n x k, k-contig), both bf16 hi/lo planes.
// 3-product split: Ah*Bh + Ah*Bl + Al*Bh (error ~2^-18).
// Tile 128(m) x 128(n), BK=32, 4 waves of 64x64, v_mfma_f32_16x16x32_bf16.
// grid (4 m-tiles, kL/128 n-tiles, CB), block 256.
// ---------------------------------------------------------------------------
__global__ __launch_bounds__(256) void gemm_mfma_kernel(
    const short* __restrict__ WtHi, const short* __restrict__ WtLo,
    const short* __restrict__ YtHi, const short* __restrict__ YtLo,
    const float* __restrict__ bias, float* __restrict__ X)
{
  __shared__ __align__(16) short AsHi[128 * 32];
  __shared__ __align__(16) short AsLo[128 * 32];
  __shared__ __align__(16) short BsHi[128 * 32];
  __shared__ __align__(16) short BsLo[128 * 32];
  const int tid = threadIdx.x;
  const int b  = blockIdx.z;
  const int m0 = blockIdx.x * 128;
  const int n0 = blockIdx.y * 128;
  const int lane = tid & 63, w = tid >> 6;
  const int wr = w >> 1, wc = w & 1;
  const int lr = lane & 15, lk = (lane >> 4) * 8;

  f32x4 acc[4][4];
  #pragma unroll
  for (int i = 0; i < 4; ++i)
    #pragma unroll
    for (int j = 0; j < 4; ++j)
      #pragma unroll
      for (int r = 0; r < 4; ++r) acc[i][j][r] = 0.f;

  const size_t abase = (size_t)m0 * kH;
  const size_t bbase = ((size_t)b * kL + n0) * kH;

  for (int k0 = 0; k0 < kH; k0 += 32) {
    #pragma unroll
    for (int p = 0; p < 2; ++p) {
      int c = tid + p * 256;
      int rr = c >> 2, ko = (c & 3) * 8;
      size_t ga = abase + (size_t)rr * kH + k0 + ko;
      *(s16x8*)&AsHi[rr * 32 + ko] = *(const s16x8*)&WtHi[ga];
      *(s16x8*)&AsLo[rr * 32 + ko] = *(const s16x8*)&WtLo[ga];
      size_t gb = bbase + (size_t)rr * kH + k0 + ko;
      *(s16x8*)&BsHi[rr * 32 + ko] = *(const s16x8*)&YtHi[gb];
      *(s16x8*)&BsLo[rr * 32 + ko] = *(const s16x8*)&YtLo[gb];
    }
    __syncthreads();
    s16x8 ah[4], al[4], bh[4], bl[4];
    #pragma unroll
    for (int f = 0; f < 4; ++f) {
      int ra = (wr * 64 + f * 16 + lr) * 32 + lk;
      ah[f] = *(const s16x8*)&AsHi[ra];
      al[f] = *(const s16x8*)&AsLo[ra];
      int rb = (wc * 64 + f * 16 + lr) * 32 + lk;
      bh[f] = *(const s16x8*)&BsHi[rb];
      bl[f] = *(const s16x8*)&BsLo[rb];
    }
    #pragma unroll
    for (int i = 0; i < 4; ++i)
      #pragma unroll
      for (int j = 0; j < 4; ++j) {
        acc[i][j] = __builtin_amdgcn_mfma_f32_16x16x32_bf16(ah[i], bh[j], acc[i][j], 0, 0, 0);
        acc[i][j] = __builtin_amdgcn_mfma_f32_16x16x32_bf16(ah[i], bl[j], acc[i][j], 0, 0, 0);
        acc[i][j] = __builtin_amdgcn_mfma_f32_16x16x32_bf16(al[i], bh[j], acc[i][j], 0, 0, 0);
      }
    __syncthreads();
  }
  // epilogue: residual add into X
  #pragma unroll
  for (int i = 0; i < 4; ++i) {
    int m = m0 + wr * 64 + i * 16 + (lane >> 4) * 4;
    #pragma unroll
    for (int j = 0; j < 4; ++j) {
      int n = n0 + wc * 64 + j * 16 + lr;
      #pragma unroll
      for (int r = 0; r < 4; ++r) {
        float* xp = &X[((size_t)b * kH + m + r) * kL + n];
        *xp += acc[i][j][r] + bias[m + r];
      }
    }
  }
}

// ---------------------------------------------------------------------------
// pooled[row] = mean_l X[row][l]
// ---------------------------------------------------------------------------
__global__ __launch_bounds__(256) void pool_kernel(const float* __restrict__ X,
                                                   float* __restrict__ pooled)
{
  int bid = blockIdx.x;
  const float* row = X + (size_t)bid * kL;
  float s = 0.f;
  for (int i = threadIdx.x; i < kL; i += 256) s += row[i];
  for (int off = 32; off > 0; off >>= 1) s += __shfl_down(s, off);
  __shared__ float p[4];
  if ((threadIdx.x & 63) == 0) p[threadIdx.x >> 6] = s;
  __syncthreads();
  if (threadIdx.x == 0) pooled[bid] = (p[0] + p[1] + p[2] + p[3]) * (1.f / kL);
}

// ---------------------------------------------------------------------------
// fusion MLP + two heads. one block per b (full batch).
// ---------------------------------------------------------------------------
__global__ __launch_bounds__(256) void head_kernel(
    const float* __restrict__ pooled, const int* __restrict__ com,
    const int* __restrict__ cou, const float* __restrict__ comE,
    const float* __restrict__ couE, const float* __restrict__ fusW,
    const float* __restrict__ fusb, const float* __restrict__ vW1,
    const float* __restrict__ vb1, const float* __restrict__ vW2,
    const float* __restrict__ vb2, const float* __restrict__ wW1,
    const float* __restrict__ wb1, const float* __restrict__ wW2,
    const float* __restrict__ wb2, float* __restrict__ out)
{
  __shared__ float feat[768];
  __shared__ float h1[512];
  __shared__ float vv[256];
  int tid = threadIdx.x;
  int b = blockIdx.x;
  int cid = com[b], ct = cou[b];
  for (int i = tid; i < 512; i += 256) feat[i] = pooled[b * kH + i];
  if (tid < 128) {
    feat[512 + tid] = comE[cid * 128 + tid];
    feat[640 + tid] = couE[ct * 128 + tid];
  }
  __syncthreads();
  #pragma unroll
  for (int jj = 0; jj < 2; jj++) {
    int j = tid + jj * 256;
    float acc = fusb[j];
    for (int i = 0; i < 768; i++) acc += feat[i] * fusW[i * kH + j];
    h1[j] = acc;
  }
  __syncthreads();
  {
    float acc = vb1[tid];
    for (int i = 0; i < 512; i++) acc += h1[i] * vW1[i * 256 + tid];
    vv[tid] = fmaxf(acc, 0.f) * vW2[tid];
  }
  __syncthreads();
  for (int s = 128; s > 0; s >>= 1) {
    if (tid < s) vv[tid] += vv[tid + s];
    __syncthreads();
  }
  if (tid == 0) out[b * 2 + 0] = vv[0] + vb2[0];
  __syncthreads();
  {
    float acc = wb1[tid];
    for (int i = 0; i < 512; i++) acc += h1[i] * wW1[i * 256 + tid];
    vv[tid] = fmaxf(acc, 0.f) * wW2[tid];
  }
  __syncthreads();
  for (int s = 128; s > 0; s >>= 1) {
    if (tid < s) vv[tid] += vv[tid + s];
    __syncthreads();
  }
  if (tid == 0) out[b * 2 + 1] = vv[0] + wb2[0];
}

}  // namespace

extern "C" void kernel_launch(void* const* d_in, const int* in_sizes, int n_in,
                              void* d_out, int out_size, void* d_ws, size_t ws_size,
                              hipStream_t stream)
{
  (void)in_sizes; (void)n_in; (void)out_size;
  const float* seq   = (const float*)d_in[0];
  const int*   com   = (const int*)d_in[1];
  const int*   cou   = (const int*)d_in[2];
  const float* encW  = (const float*)d_in[3];
  const float* encb  = (const float*)d_in[4];
  const float* comE  = (const float*)d_in[5];
  const float* couE  = (const float*)d_in[6];
  const float* logst = (const float*)d_in[7];
  const float* Ar    = (const float*)d_in[8];
  const float* Ai    = (const float*)d_in[9];
  const float* Br    = (const float*)d_in[10];
  const float* Bi    = (const float*)d_in[11];
  const float* Cp    = (const float*)d_in[12];
  const float* Dp    = (const float*)d_in[13];
  const float* outW  = (const float*)d_in[14];
  const float* outb  = (const float*)d_in[15];
  const float* lng   = (const float*)d_in[16];
  const float* lnb   = (const float*)d_in[17];
  const float* fusW  = (const float*)d_in[18];
  const float* fusb  = (const float*)d_in[19];
  const float* vW1   = (const float*)d_in[20];
  const float* vb1   = (const float*)d_in[21];
  const float* vW2   = (const float*)d_in[22];
  const float* vb2   = (const float*)d_in[23];
  const float* wW1   = (const float*)d_in[24];
  const float* wb1   = (const float*)d_in[25];
  const float* wW2   = (const float*)d_in[26];
  const float* wb2   = (const float*)d_in[27];
  float* out = (float*)d_out;

  // ---- adaptive workspace sizing (in floats) ----
  const size_t F_KF1   = (size_t)kH * 2049 * 2;       // one layer's spectrum
  const size_t F_COEFF = (size_t)4 * kH * kN * 4;     // all-layer coeffs
  const size_t F_TW    = 8192;
  const size_t F_POOL  = (size_t)kB * kH;
  const size_t F_WT    = (size_t)4 * kH * kH;         // 2 bf16 planes, 4 layers
  size_t nws = ws_size / sizeof(float);
  auto need = [&](size_t cb, bool kfall) -> size_t {
    return (kfall ? 4 : 1) * F_KF1 + F_COEFF + F_TW + F_POOL + F_WT
         + 2 * cb * (size_t)kL              // mu + rstd
         + 2 * cb * (size_t)kH * kL         // X + Y (fp32)
         + cb * (size_t)kH * kL;            // Yt hi+lo (bf16 planes)
  };
  const int cand[7] = {64, 32, 16, 8, 4, 2, 1};
  int CB = 0; bool kfAll = true;
  for (int i = 0; i < 7 && !CB; i++)
    if (need(cand[i], true) <= nws) { CB = cand[i]; kfAll = true; }
  for (int i = 0; i < 7 && !CB; i++)
    if (need(cand[i], false) <= nws) { CB = cand[i]; kfAll = false; }
  if (!CB) { CB = 1; kfAll = false; }

  float* ws = (float*)d_ws;
  size_t o = 0;
  float2* Kf    = (float2*)(ws + o); o += (kfAll ? 4 : 1) * F_KF1;
  float4* coeff = (float4*)(ws + o); o += F_COEFF;
  float2* twst  = (float2*)(ws + o); o += F_TW;
  float*  pooled= ws + o;            o += F_POOL;
  short*  WtHi  = (short*)(ws + o);  o += F_WT / 2;
  short*  WtLo  = (short*)(ws + o);  o += F_WT / 2;
  float*  mu    = ws + o;            o += (size_t)CB * kL;
  float*  rstd  = ws + o;            o += (size_t)CB * kL;
  float*  X     = ws + o;            o += (size_t)CB * kH * kL;
  float*  Yb    = ws + o;            o += (size_t)CB * kH * kL;
  short*  YtHi  = (short*)(ws + o);  o += (size_t)CB * kH * kL / 2;
  short*  YtLo  = (short*)(ws + o);  o += (size_t)CB * kH * kL / 2;

  twiddle_init_kernel<<<16, 256, 0, stream>>>(twst);
  coeff_kernel<<<512, 256, 0, stream>>>(logst, Ar, Ai, Br, Bi, Cp, coeff);
  wprep_kernel<<<dim3(16, 16, 4), 256, 0, stream>>>(outW, WtHi, WtLo);
  if (kfAll) kfft_kernel<<<4 * kH, 256, 0, stream>>>(coeff, twst, Kf);

  const int nchunk = kB / CB;
  for (int c = 0; c < nchunk; c++) {
    const int b0 = c * CB;
    encoder_kernel<<<CB * kH * (kL / 256), 256, 0, stream>>>(
        seq + (size_t)b0 * kL * 5, encW, encb, X);
    for (int layer = 0; layer < 4; layer++) {
      if (!kfAll)
        kfft_kernel<<<kH, 256, 0, stream>>>(
            coeff + (size_t)layer * kH * kN, twst, Kf);
      ln_stats_kernel<<<CB * (kL / 64), 256, 0, stream>>>(X, mu, rstd);
      conv_kernel<<<CB * kH, 256, 0, stream>>>(
          X, mu, rstd, lng + layer * kH, lnb + layer * kH, Dp + layer * kH,
          kfAll ? Kf + (size_t)layer * kH * 2049 : Kf, twst, Yb);
      ytrans_kernel<<<dim3(kL / 64, kH / 64, CB), 256, 0, stream>>>(Yb, YtHi, YtLo);
      gemm_mfma_kernel<<<dim3(4, kL / 128, CB), 256, 0, stream>>>(
          WtHi + (size_t)layer * kH * kH, WtLo + (size_t)layer * kH * kH,
          YtHi, YtLo, outb + layer * kH, X);
    }
    pool_kernel<<<CB * kH, 256, 0, stream>>>(X, pooled + (size_t)b0 * kH);
  }

  head_kernel<<<kB, 256, 0, stream>>>(pooled, com, cou, comE, couE, fusW, fusb,
                                      vW1, vb1, vW2, vb2, wW1, wb1, wW2, wb2, out);
}

// Round 10
// 6657.155 us; speedup vs baseline: 1.4352x; 1.0253x over previous
//
#include <hip/hip_runtime.h>
#include <cmath>

namespace {

constexpr int kB = 64;
constexpr int kL = 2048;
constexpr int kH = 512;
constexpr int kN = 64;

typedef short s16x8 __attribute__((ext_vector_type(8)));
typedef float f32x4 __attribute__((ext_vector_type(4)));

// bf16 round-to-nearest-even split: f ~= hi + lo (both bf16)
__device__ __forceinline__ void bf16_split(float f, unsigned short& hi, unsigned short& lo)
{
  unsigned u = __float_as_uint(f);
  unsigned rh = u + 0x7FFFu + ((u >> 16) & 1u);
  hi = (unsigned short)(rh >> 16);
  float fh = __uint_as_float((unsigned)hi << 16);
  float fl = f - fh;
  unsigned u2 = __float_as_uint(fl);
  unsigned r2 = u2 + 0x7FFFu + ((u2 >> 16) & 1u);
  lo = (unsigned short)(r2 >> 16);
}

// ---------------------------------------------------------------------------
// Twiddle table: twst[(1<<(s-1))-1 + j] = exp(-2*pi*i*j / (1<<s)), s = 1..12.
// ---------------------------------------------------------------------------
__global__ __launch_bounds__(256) void twiddle_init_kernel(float2* __restrict__ twst)
{
  int idx = blockIdx.x * 256 + threadIdx.x;
  if (idx >= 4095) return;
  int v  = idx + 1;
  int fl = 31 - __clz(v);          // v in [2^fl, 2^(fl+1))
  int j  = v - (1 << fl);
  int len = 1 << (fl + 1);
  double ang = -6.283185307179586476925286766559 * (double)j / (double)len;
  twst[idx] = make_float2((float)cos(ang), (float)sin(ang));
}

// ---------------------------------------------------------------------------
// 2048-point complex FFT in LDS. Radix-4 passes (pairs of radix-2 DIT stages
// composed). Bit-reversed input permutation, natural-order output.
// 5 radix-4 passes (s=1,3,5,7,9) + final radix-2 (s=11).
// ---------------------------------------------------------------------------
__device__ __forceinline__ void fft2048_lds(float* re, float* im,
                                            const float2* twsl, int tid)
{
  for (int idx = tid; idx < 2048; idx += 256) {
    int r = (int)(__brev((unsigned)idx) >> 21);
    if (r > idx) {
      float a = re[idx]; re[idx] = re[r]; re[r] = a;
      float b = im[idx]; im[idx] = im[r]; im[r] = b;
    }
  }
  __syncthreads();
  #pragma unroll
  for (int s = 1; s <= 9; s += 2) {
    const int h = 1 << (s - 1);
    #pragma unroll
    for (int u = 0; u < 2; ++u) {
      const int q = tid + (u << 8);          // quad index in [0,512)
      if (s == 1) {
        // h=1, j=0, w1=w2=1; contiguous quad -> float4 fast path
        const int p = q << 2;
        float4 xr = *(const float4*)&re[p];
        float4 xi = *(const float4*)&im[p];
        float u0r = xr.x + xr.y, u0i = xi.x + xi.y;
        float u1r = xr.x - xr.y, u1i = xi.x - xi.y;
        float u2r = xr.z + xr.w, u2i = xi.z + xi.w;
        float u3r = xr.z - xr.w, u3i = xi.z - xi.w;
        float4 orr, oii;
        orr.x = u0r + u2r; oii.x = u0i + u2i;
        orr.z = u0r - u2r; oii.z = u0i - u2i;
        orr.y = u1r + u3i; oii.y = u1i - u3r;   // u1 + (-i)*u3
        orr.w = u1r - u3i; oii.w = u1i + u3r;   // u1 - (-i)*u3
        *(float4*)&re[p] = orr;
        *(float4*)&im[p] = oii;
      } else {
        const int j = q & (h - 1);
        const int G = q >> (s - 1);
        const int p = (G << (s + 1)) + j;
        float x0r = re[p],         x0i = im[p];
        float x1r = re[p + h],     x1i = im[p + h];
        float x2r = re[p + 2 * h], x2i = im[p + 2 * h];
        float x3r = re[p + 3 * h], x3i = im[p + 3 * h];
        float2 w1 = twsl[h - 1 + j];
        float2 w2 = twsl[2 * h - 1 + j];
        // stage s (both radix-2 butterflies share w1)
        float t1r = x1r * w1.x - x1i * w1.y, t1i = x1r * w1.y + x1i * w1.x;
        float t3r = x3r * w1.x - x3i * w1.y, t3i = x3r * w1.y + x3i * w1.x;
        float u0r = x0r + t1r, u0i = x0i + t1i;
        float u1r = x0r - t1r, u1i = x0i - t1i;
        float u2r = x2r + t3r, u2i = x2i + t3i;
        float u3r = x2r - t3r, u3i = x2i - t3i;
        // stage s+1: pair (p, p+2h) uses w2; pair (p+h, p+3h) uses -i*w2
        float m0r = u2r * w2.x - u2i * w2.y, m0i = u2r * w2.y + u2i * w2.x;
        float m1r = u3r * w2.x - u3i * w2.y, m1i = u3r * w2.y + u3i * w2.x;
        re[p]         = u0r + m0r; im[p]         = u0i + m0i;
        re[p + 2 * h] = u0r - m0r; im[p + 2 * h] = u0i - m0i;
        re[p + h]     = u1r + m1i; im[p + h]     = u1i - m1r;
        re[p + 3 * h] = u1r - m1i; im[p + 3 * h] = u1i + m1r;
      }
    }
    __syncthreads();
  }
  // final radix-2 stage s=11 (half=1024, g=0, j=bf)
  #pragma unroll
  for (int w = 0; w < 4; ++w) {
    int j  = tid + (w << 8);
    int p1 = j + 1024;
    float2 tw = twsl[1023 + j];
    float xr = re[p1], xi = im[p1];
    float tr = xr * tw.x - xi * tw.y;
    float ti = xr * tw.y + xi * tw.x;
    float ur = re[j], ui = im[j];
    re[j]  = ur + tr; im[j]  = ui + ti;
    re[p1] = ur - tr; im[p1] = ui - ti;
  }
  __syncthreads();
}

// ---------------------------------------------------------------------------
// Encoder (chunk): X[bc][h][l] = sum_d seq[bc][l][d]*encW[d][h] + encb[h]
// ---------------------------------------------------------------------------
__global__ __launch_bounds__(256) void encoder_kernel(
    const float* __restrict__ seq, const float* __restrict__ encW,
    const float* __restrict__ encb, float* __restrict__ X)
{
  int bid = blockIdx.x;
  int lt = bid & 7;
  int h  = (bid >> 3) & 511;
  int bc = bid >> 12;              // local chunk batch
  int l  = lt * 256 + threadIdx.x;
  const float* sp = seq + ((size_t)bc * kL + l) * 5;
  float acc = encb[h];
  #pragma unroll
  for (int d = 0; d < 5; d++) acc += sp[d] * encW[d * kH + h];
  X[((size_t)bc * kH + h) * kL + l] = acc;
}

// ---------------------------------------------------------------------------
// LN stats over H per (bc,l): mu, rstd. grid: CB*32; block 256 = 4 hg x 64 l
// ---------------------------------------------------------------------------
__global__ __launch_bounds__(256) void ln_stats_kernel(
    const float* __restrict__ X, float* __restrict__ mu, float* __restrict__ rstd)
{
  int b  = blockIdx.x >> 5;        // local chunk batch
  int l0 = (blockIdx.x & 31) * 64;
  int g  = threadIdx.x >> 6;
  int lt = threadIdx.x & 63;
  const float* xb = X + (size_t)b * kH * kL + l0 + lt;
  float s = 0.f, q = 0.f;
  for (int h = g; h < kH; h += 4) {
    float v = xb[(size_t)h * kL];
    s += v; q += v * v;
  }
  __shared__ float ss[4][64], qq[4][64];
  ss[g][lt] = s; qq[g][lt] = q;
  __syncthreads();
  if (threadIdx.x < 64) {
    float S = ss[0][threadIdx.x] + ss[1][threadIdx.x] + ss[2][threadIdx.x] + ss[3][threadIdx.x];
    float Q = qq[0][threadIdx.x] + qq[1][threadIdx.x] + qq[2][threadIdx.x] + qq[3][threadIdx.x];
    float m   = S * (1.f / kH);
    float var = Q * (1.f / kH) - m * m;
    mu[b * kL + l0 + threadIdx.x]   = m;
    rstd[b * kL + l0 + threadIdx.x] = 1.f / sqrtf(var + 1e-5f);
  }
}

// ---------------------------------------------------------------------------
// Per-(layer,h,n) SSM coefficients for ALL 4 layers at once.
// Also stores stepd[idx] = dA = exp(dt*A)  (the kfft recurrence step).
// ---------------------------------------------------------------------------
__global__ __launch_bounds__(256) void coeff_kernel(
    const float* __restrict__ logst, const float* __restrict__ Are,
    const float* __restrict__ Aim, const float* __restrict__ Bre,
    const float* __restrict__ Bim, const float* __restrict__ Cp,
    float4* __restrict__ coeff, float2* __restrict__ stepd)
{
  int idx = blockIdx.x * 256 + threadIdx.x;   // (layer*512 + h)*64 + n
  float dt = expf(logst[idx >> 6]);           // logst is [4][512] flat
  float ar = -expf(Are[idx]);
  float ai = Aim[idx];
  float wre = dt * ar, wim = dt * ai;
  float er  = expf(wre);
  float dAr = er * cosf(wim), dAi = er * sinf(wim);
  float numr = dAr - 1.f, numi = dAi;
  float den  = ar * ar + ai * ai;
  float qr = (numr * ar + numi * ai) / den;     // (dA-1)/A
  float qi = (numi * ar - numr * ai) / den;
  float br = Bre[idx], bi = Bim[idx];
  float tr = dt * (br * qr - bi * qi);          // dB
  float ti = dt * (br * qi + bi * qr);
  float cr = Cp[2 * idx], ci = Cp[2 * idx + 1];
  float ccr = 2.f * (cr * tr - ci * ti);        // 2*C*dB
  float cci = 2.f * (cr * ti + ci * tr);
  coeff[idx] = make_float4(wre, wim, ccr, cci);
  stepd[idx] = make_float2(dAr, dAi);
}

// ---------------------------------------------------------------------------
// SSM kernel row k[l] = Re(sum_n cc*exp(w*l)) via geometric recurrence:
// thread owns contiguous l in [8*tid, 8*tid+8); per state: one base
// exp(w*8*tid) (single large-arg sincos) then 7 complex mults by dA=exp(w).
// Then half-spectrum of the length-4096 zero-padded rFFT.
// One block per grid row (layer*h or h).
// ---------------------------------------------------------------------------
__global__ __launch_bounds__(256) void kfft_kernel(
    const float4* __restrict__ coeff, const float2* __restrict__ stepd,
    const float2* __restrict__ twst, float2* __restrict__ Kf)
{
  __shared__ float sm[2048 * 2 + 2047 * 2];
  float* cre  = sm;
  float* cim  = sm + 2048;
  float2* twsl = (float2*)(sm + 4096);
  int tid = threadIdx.x;
  int row = blockIdx.x;
  for (int idx = tid; idx < 2047; idx += 256) twsl[idx] = twst[idx];
  float kreg[8] = {0.f, 0.f, 0.f, 0.f, 0.f, 0.f, 0.f, 0.f};
  const float4* ch = coeff + (size_t)row * kN;
  const float2* sh = stepd + (size_t)row * kN;
  const float lbase = (float)(tid * 8);
  for (int n = 0; n < kN; n++) {
    float4 c  = ch[n];
    float2 st = sh[n];
    float er = expf(c.x * lbase);
    float sn, cs;
    sincosf(c.y * lbase, &sn, &cs);
    float gr = er * cs, gi = er * sn;          // exp(w * 8*tid)
    #pragma unroll
    for (int m = 0; m < 8; m++) {
      kreg[m] += c.z * gr - c.w * gi;          // Re(cc * exp(w*l))
      float ngr = gr * st.x - gi * st.y;       // *= dA
      float ngi = gr * st.y + gi * st.x;
      gr = ngr; gi = ngi;
    }
  }
  // pack real k (zero-padded to 4096) into 2048 complex: c[j]=k[2j]+i*k[2j+1]
  // contiguous ownership: c[4t+m] = k[8t+2m] + i*k[8t+2m+1]
  float4 cr4 = make_float4(kreg[0], kreg[2], kreg[4], kreg[6]);
  float4 ci4 = make_float4(kreg[1], kreg[3], kreg[5], kreg[7]);
  *(float4*)&cre[4 * tid] = cr4;
  *(float4*)&cim[4 * tid] = ci4;
  for (int j = 1024 + tid; j < 2048; j += 256) { cre[j] = 0.f; cim[j] = 0.f; }
  __syncthreads();
  fft2048_lds(cre, cim, twsl, tid);
  // unpack: U[k] = Fe[k] + w4096^k * Fo[k]
  float2* kfh = Kf + (size_t)row * 2049;
  #pragma unroll
  for (int i = 0; i < 8; i++) {
    int k  = i * 256 + tid;
    int mk = (2048 - k) & 2047;
    float ar = cre[k], ai2 = cim[k], br = cre[mk], bi = cim[mk];
    float fer = 0.5f * (ar + br),  fei = 0.5f * (ai2 - bi);
    float fo_r = 0.5f * (ai2 + bi), foi = 0.5f * (br - ar);
    float2 w = twst[2047 + k];
    kfh[k] = make_float2(fer + w.x * fo_r - w.y * foi,
                         fei + w.x * foi + w.y * fo_r);
  }
  if (tid == 0) kfh[2048] = make_float2(cre[0] - cim[0], 0.f);
}

// ---------------------------------------------------------------------------
// Fused: inline LN apply -> rFFT(z) -> x Kf -> irFFT -> +D*z -> GELU -> Y
// one block per (bc,h) row. LDS: 48 KB
// ---------------------------------------------------------------------------
__global__ __launch_bounds__(256) void conv_kernel(
    const float* __restrict__ X, const float* __restrict__ mu,
    const float* __restrict__ rstd, const float* __restrict__ gam,
    const float* __restrict__ bet, const float* __restrict__ Dp,
    const float2* __restrict__ Kf, const float2* __restrict__ twst,
    float* __restrict__ Y)
{
  __shared__ float sm[12288];
  float* cre = sm;
  float* cim = sm + 2048;
  float* Ure = sm + 4096;   // 2049
  float* Uim = sm + 6145;   // 2049
  float2* twsl = (float2*)(sm + 8194);  // 2047 float2
  int tid = threadIdx.x;
  int bid = blockIdx.x;          // bc*512 + h
  int b = bid >> 9, h = bid & 511;
  for (int idx = tid; idx < 2047; idx += 256) twsl[idx] = twst[idx];
  const float* xrow  = X + (size_t)bid * kL;
  const float* murow = mu + b * kL;
  const float* rrow  = rstd + b * kL;
  float gam_h = gam[h], bet_h = bet[h], d_h = Dp[h];
  float zreg[8];
  #pragma unroll
  for (int i = 0; i < 8; i++) {
    int l = i * 256 + tid;
    zreg[i] = (xrow[l] - murow[l]) * rrow[l] * gam_h + bet_h;
  }
  // pack z (zero-padded to 4096)
  #pragma unroll
  for (int i = 0; i < 8; i++) {
    int j = i * 128 + (tid >> 1);
    if (tid & 1) cim[j] = zreg[i]; else cre[j] = zreg[i];
  }
  for (int j = 1024 + tid; j < 2048; j += 256) { cre[j] = 0.f; cim[j] = 0.f; }
  __syncthreads();
  fft2048_lds(cre, cim, twsl, tid);
  // unpack to half-spectrum U[0..2048]
  #pragma unroll
  for (int i = 0; i < 8; i++) {
    int k  = i * 256 + tid;
    int mk = (2048 - k) & 2047;
    float ar = cre[k], ai2 = cim[k], br = cre[mk], bi = cim[mk];
    float fer = 0.5f * (ar + br),  fei = 0.5f * (ai2 - bi);
    float fo_r = 0.5f * (ai2 + bi), foi = 0.5f * (br - ar);
    float2 w = twst[2047 + k];
    Ure[k] = fer + w.x * fo_r - w.y * foi;
    Uim[k] = fei + w.x * foi + w.y * fo_r;
  }
  if (tid == 0) { Ure[2048] = cre[0] - cim[0]; Uim[2048] = 0.f; }
  __syncthreads();
  // P = U*Kf ; repack C'[k] = E' + i O' ; store conj(C') for inverse-by-conj
  const float2* kfh = Kf + (size_t)h * 2049;
  #pragma unroll
  for (int i = 0; i < 8; i++) {
    int k  = i * 256 + tid;
    int mk = 2048 - k;
    float2 k1 = kfh[k], k2 = kfh[mk];
    float Ukr = Ure[k],  Uki = Uim[k];
    float Umr = Ure[mk], Umi = Uim[mk];
    float Pr = Ukr * k1.x - Uki * k1.y, Pi = Ukr * k1.y + Uki * k1.x;
    float Qr = Umr * k2.x - Umi * k2.y, Qi = Umr * k2.y + Umi * k2.x;
    float epr = 0.5f * (Pr + Qr), epi = 0.5f * (Pi - Qi);
    float dr  = 0.5f * (Pr - Qr), di  = 0.5f * (Pi + Qi);
    float2 w = twst[2047 + k];
    float opr = w.x * dr + w.y * di;     // w^{-k} * (..)
    float opi = w.x * di - w.y * dr;
    cre[k] = epr - opi;                  // Re C'
    cim[k] = -(epi + opr);               // -Im C'  (conj)
  }
  __syncthreads();
  fft2048_lds(cre, cim, twsl, tid);
  // y[2j] = Re/2048, y[2j+1] = -Im/2048 ; then skip D*z, exact GELU
  float* yrow = Y + (size_t)bid * kL;
  constexpr float inv = 1.f / 2048.f;
  #pragma unroll
  for (int i = 0; i < 8; i++) {
    int l = i * 256 + tid;
    int j = i * 128 + (tid >> 1);
    float v = (tid & 1) ? (-cim[j]) : cre[j];
    v = v * inv + d_h * zreg[i];
    yrow[l] = 0.5f * v * (1.f + erff(v * 0.70710678f));
  }
}

// ---------------------------------------------------------------------------
// W prep (all 4 layers once): Wt_hi/lo[m][k] = split(W[k][m]).  32x32 LDS tile.
// grid (16,16,4), block 256.
// ---------------------------------------------------------------------------
__global__ __launch_bounds__(256) void wprep_kernel(
    const float* __restrict__ W, short* __restrict__ WtHi, short* __restrict__ WtLo)
{
  __shared__ float t[32][33];
  int l = blockIdx.z, k0 = blockIdx.y * 32, m0 = blockIdx.x * 32;
  int c = threadIdx.x & 31, r0 = threadIdx.x >> 5;   // 8 rows per pass
  const float* wp = W + ((size_t)l * kH + k0) * kH + m0;
  #pragma unroll
  for (int it = 0; it < 4; ++it) {
    int r = r0 + it * 8;
    t[r][c] = wp[(size_t)r * kH + c];
  }
  __syncthreads();
  #pragma unroll
  for (int it = 0; it < 4; ++it) {
    int mr = r0 + it * 8;
    float v = t[c][mr];                 // = W[k0+c][m0+mr]
    unsigned short hi, lo;
    bf16_split(v, hi, lo);
    size_t oa = ((size_t)l * kH + m0 + mr) * kH + k0 + c;
    WtHi[oa] = (short)hi;
    WtLo[oa] = (short)lo;
  }
}

// ---------------------------------------------------------------------------
// Y transpose+split: Yt_hi/lo[b][n][k] = split(Y[b][k][n]). 64x64 LDS tile.
// grid (kL/64, kH/64, CB), block 256.
// ---------------------------------------------------------------------------
__global__ __launch_bounds__(256) void ytrans_kernel(
    const float* __restrict__ Y, short* __restrict__ YtHi, short* __restrict__ YtLo)
{
  __shared__ float t[64][65];
  int b = blockIdx.z, k0 = blockIdx.y * 64, n0 = blockIdx.x * 64;
  int c = threadIdx.x & 63, r0 = threadIdx.x >> 6;   // 4 rows per pass
  const float* yp = Y + ((size_t)b * kH + k0) * kL + n0;
  #pragma unroll
  for (int it = 0; it < 16; ++it) {
    int r = r0 + it * 4;
    t[r][c] = yp[(size_t)r * kL + c];
  }
  __syncthreads();
  #pragma unroll
  for (int it = 0; it < 16; ++it) {
    int nr = r0 + it * 4;
    float v = t[c][nr];                 // = Y[b][k0+c][n0+nr]
    unsigned short hi, lo;
    bf16_split(v, hi, lo);
    size_t oa = ((size_t)b * kL + n0 + nr) * kH + k0 + c;
    YtHi[oa] = (short)hi;
    YtLo[oa] = (short)lo;
  }
}

// ---------------------------------------------------------------------------
// MFMA GEMM: X[b][m][n] += bias[m] + sum_k W[k][m]*Y[b][k][n]
// A = Wt (m x k, k-contig), B = Yt (n x k, k-contig), both bf16 hi/lo planes.
// 3-product split: Ah*Bh + Ah*Bl + Al*Bh (error ~2^-18).
// Tile 128(m) x 128(n), BK=32, 4 waves of 64x64, v_mfma_f32_16x16x32_bf16.
// grid (4 m-tiles, kL/128 n-tiles, CB), block 256.
// ---------------------------------------------------------------------------
__global__ __launch_bounds__(256) void gemm_mfma_kernel(
    const short* __restrict__ WtHi, const short* __restrict__ WtLo,
    const short* __restrict__ YtHi, const short* __restrict__ YtLo,
    const float* __restrict__ bias, float* __restrict__ X)
{
  __shared__ __align__(16) short AsHi[128 * 32];
  __shared__ __align__(16) short AsLo[128 * 32];
  __shared__ __align__(16) short BsHi[128 * 32];
  __shared__ __align__(16) short BsLo[128 * 32];
  const int tid = threadIdx.x;
  const int b  = blockIdx.z;
  const int m0 = blockIdx.x * 128;
  const int n0 = blockIdx.y * 128;
  const int lane = tid & 63, w = tid >> 6;
  const int wr = w >> 1, wc = w & 1;
  const int lr = lane & 15, lk = (lane >> 4) * 8;

  f32x4 acc[4][4];
  #pragma unroll
  for (int i = 0; i < 4; ++i)
    #pragma unroll
    for (int j = 0; j < 4; ++j)
      #pragma unroll
      for (int r = 0; r < 4; ++r) acc[i][j][r] = 0.f;

  const size_t abase = (size_t)m0 * kH;
  const size_t bbase = ((size_t)b * kL + n0) * kH;

  for (int k0 = 0; k0 < kH; k0 += 32) {
    #pragma unroll
    for (int p = 0; p < 2; ++p) {
      int c = tid + p * 256;
      int rr = c >> 2, ko = (c & 3) * 8;
      size_t ga = abase + (size_t)rr * kH + k0 + ko;
      *(s16x8*)&AsHi[rr * 32 + ko] = *(const s16x8*)&WtHi[ga];
      *(s16x8*)&AsLo[rr * 32 + ko] = *(const s16x8*)&WtLo[ga];
      size_t gb = bbase + (size_t)rr * kH + k0 + ko;
      *(s16x8*)&BsHi[rr * 32 + ko] = *(const s16x8*)&YtHi[gb];
      *(s16x8*)&BsLo[rr * 32 + ko] = *(const s16x8*)&YtLo[gb];
    }
    __syncthreads();
    s16x8 ah[4], al[4], bh[4], bl[4];
    #pragma unroll
    for (int f = 0; f < 4; ++f) {
      int ra = (wr * 64 + f * 16 + lr) * 32 + lk;
      ah[f] = *(const s16x8*)&AsHi[ra];
      al[f] = *(const s16x8*)&AsLo[ra];
      int rb = (wc * 64 + f * 16 + lr) * 32 + lk;
      bh[f] = *(const s16x8*)&BsHi[rb];
      bl[f] = *(const s16x8*)&BsLo[rb];
    }
    #pragma unroll
    for (int i = 0; i < 4; ++i)
      #pragma unroll
      for (int j = 0; j < 4; ++j) {
        acc[i][j] = __builtin_amdgcn_mfma_f32_16x16x32_bf16(ah[i], bh[j], acc[i][j], 0, 0, 0);
        acc[i][j] = __builtin_amdgcn_mfma_f32_16x16x32_bf16(ah[i], bl[j], acc[i][j], 0, 0, 0);
        acc[i][j] = __builtin_amdgcn_mfma_f32_16x16x32_bf16(al[i], bh[j], acc[i][j], 0, 0, 0);
      }
    __syncthreads();
  }
  // epilogue: residual add into X
  #pragma unroll
  for (int i = 0; i < 4; ++i) {
    int m = m0 + wr * 64 + i * 16 + (lane >> 4) * 4;
    #pragma unroll
    for (int j = 0; j < 4; ++j) {
      int n = n0 + wc * 64 + j * 16 + lr;
      #pragma unroll
      for (int r = 0; r < 4; ++r) {
        float* xp = &X[((size_t)b * kH + m + r) * kL + n];
        *xp += acc[i][j][r] + bias[m + r];
      }
    }
  }
}

// ---------------------------------------------------------------------------
// pooled[row] = mean_l X[row][l]
// ---------------------------------------------------------------------------
__global__ __launch_bounds__(256) void pool_kernel(const float* __restrict__ X,
                                                   float* __restrict__ pooled)
{
  int bid = blockIdx.x;
  const float* row = X + (size_t)bid * kL;
  float s = 0.f;
  for (int i = threadIdx.x; i < kL; i += 256) s += row[i];
  for (int off = 32; off > 0; off >>= 1) s += __shfl_down(s, off);
  __shared__ float p[4];
  if ((threadIdx.x & 63) == 0) p[threadIdx.x >> 6] = s;
  __syncthreads();
  if (threadIdx.x == 0) pooled[bid] = (p[0] + p[1] + p[2] + p[3]) * (1.f / kL);
}

// ---------------------------------------------------------------------------
// fusion MLP + two heads. one block per b (full batch).
// ---------------------------------------------------------------------------
__global__ __launch_bounds__(256) void head_kernel(
    const float* __restrict__ pooled, const int* __restrict__ com,
    const int* __restrict__ cou, const float* __restrict__ comE,
    const float* __restrict__ couE, const float* __restrict__ fusW,
    const float* __restrict__ fusb, const float* __restrict__ vW1,
    const float* __restrict__ vb1, const float* __restrict__ vW2,
    const float* __restrict__ vb2, const float* __restrict__ wW1,
    const float* __restrict__ wb1, const float* __restrict__ wW2,
    const float* __restrict__ wb2, float* __restrict__ out)
{
  __shared__ float feat[768];
  __shared__ float h1[512];
  __shared__ float vv[256];
  int tid = threadIdx.x;
  int b = blockIdx.x;
  int cid = com[b], ct = cou[b];
  for (int i = tid; i < 512; i += 256) feat[i] = pooled[b * kH + i];
  if (tid < 128) {
    feat[512 + tid] = comE[cid * 128 + tid];
    feat[640 + tid] = couE[ct * 128 + tid];
  }
  __syncthreads();
  #pragma unroll
  for (int jj = 0; jj < 2; jj++) {
    int j = tid + jj * 256;
    float acc = fusb[j];
    for (int i = 0; i < 768; i++) acc += feat[i] * fusW[i * kH + j];
    h1[j] = acc;
  }
  __syncthreads();
  {
    float acc = vb1[tid];
    for (int i = 0; i < 512; i++) acc += h1[i] * vW1[i * 256 + tid];
    vv[tid] = fmaxf(acc, 0.f) * vW2[tid];
  }
  __syncthreads();
  for (int s = 128; s > 0; s >>= 1) {
    if (tid < s) vv[tid] += vv[tid + s];
    __syncthreads();
  }
  if (tid == 0) out[b * 2 + 0] = vv[0] + vb2[0];
  __syncthreads();
  {
    float acc = wb1[tid];
    for (int i = 0; i < 512; i++) acc += h1[i] * wW1[i * 256 + tid];
    vv[tid] = fmaxf(acc, 0.f) * wW2[tid];
  }
  __syncthreads();
  for (int s = 128; s > 0; s >>= 1) {
    if (tid < s) vv[tid] += vv[tid + s];
    __syncthreads();
  }
  if (tid == 0) out[b * 2 + 1] = vv[0] + wb2[0];
}

}  // namespace

extern "C" void kernel_launch(void* const* d_in, const int* in_sizes, int n_in,
                              void* d_out, int out_size, void* d_ws, size_t ws_size,
                              hipStream_t stream)
{
  (void)in_sizes; (void)n_in; (void)out_size;
  const float* seq   = (const float*)d_in[0];
  const int*   com   = (const int*)d_in[1];
  const int*   cou   = (const int*)d_in[2];
  const float* encW  = (const float*)d_in[3];
  const float* encb  = (const float*)d_in[4];
  const float* comE  = (const float*)d_in[5];
  const float* couE  = (const float*)d_in[6];
  const float* logst = (const float*)d_in[7];
  const float* Ar    = (const float*)d_in[8];
  const float* Ai    = (const float*)d_in[9];
  const float* Br    = (const float*)d_in[10];
  const float* Bi    = (const float*)d_in[11];
  const float* Cp    = (const float*)d_in[12];
  const float* Dp    = (const float*)d_in[13];
  const float* outW  = (const float*)d_in[14];
  const float* outb  = (const float*)d_in[15];
  const float* lng   = (const float*)d_in[16];
  const float* lnb   = (const float*)d_in[17];
  const float* fusW  = (const float*)d_in[18];
  const float* fusb  = (const float*)d_in[19];
  const float* vW1   = (const float*)d_in[20];
  const float* vb1   = (const float*)d_in[21];
  const float* vW2   = (const float*)d_in[22];
  const float* vb2   = (const float*)d_in[23];
  const float* wW1   = (const float*)d_in[24];
  const float* wb1   = (const float*)d_in[25];
  const float* wW2   = (const float*)d_in[26];
  const float* wb2   = (const float*)d_in[27];
  float* out = (float*)d_out;

  // ---- adaptive workspace sizing (in floats) ----
  const size_t F_KF1   = (size_t)kH * 2049 * 2;       // one layer's spectrum
  const size_t F_COEFF = (size_t)4 * kH * kN * 4;     // all-layer coeffs
  const size_t F_STEP  = (size_t)4 * kH * kN * 2;     // all-layer dA steps
  const size_t F_TW    = 8192;
  const size_t F_POOL  = (size_t)kB * kH;
  const size_t F_WT    = (size_t)4 * kH * kH;         // 2 bf16 planes, 4 layers
  size_t nws = ws_size / sizeof(float);
  auto need = [&](size_t cb, bool kfall) -> size_t {
    return (kfall ? 4 : 1) * F_KF1 + F_COEFF + F_STEP + F_TW + F_POOL + F_WT
         + 2 * cb * (size_t)kL              // mu + rstd
         + 2 * cb * (size_t)kH * kL         // X + Y (fp32)
         + cb * (size_t)kH * kL;            // Yt hi+lo (bf16 planes)
  };
  const int cand[7] = {64, 32, 16, 8, 4, 2, 1};
  int CB = 0; bool kfAll = true;
  for (int i = 0; i < 7 && !CB; i++)
    if (need(cand[i], true) <= nws) { CB = cand[i]; kfAll = true; }
  for (int i = 0; i < 7 && !CB; i++)
    if (need(cand[i], false) <= nws) { CB = cand[i]; kfAll = false; }
  if (!CB) { CB = 1; kfAll = false; }

  float* ws = (float*)d_ws;
  size_t o = 0;
  float2* Kf    = (float2*)(ws + o); o += (kfAll ? 4 : 1) * F_KF1;
  float4* coeff = (float4*)(ws + o); o += F_COEFF;
  float2* stepd = (float2*)(ws + o); o += F_STEP;
  float2* twst  = (float2*)(ws + o); o += F_TW;
  float*  pooled= ws + o;            o += F_POOL;
  short*  WtHi  = (short*)(ws + o);  o += F_WT / 2;
  short*  WtLo  = (short*)(ws + o);  o += F_WT / 2;
  float*  mu    = ws + o;            o += (size_t)CB * kL;
  float*  rstd  = ws + o;            o += (size_t)CB * kL;
  float*  X     = ws + o;            o += (size_t)CB * kH * kL;
  float*  Yb    = ws + o;            o += (size_t)CB * kH * kL;
  short*  YtHi  = (short*)(ws + o);  o += (size_t)CB * kH * kL / 2;
  short*  YtLo  = (short*)(ws + o);  o += (size_t)CB * kH * kL / 2;

  twiddle_init_kernel<<<16, 256, 0, stream>>>(twst);
  coeff_kernel<<<512, 256, 0, stream>>>(logst, Ar, Ai, Br, Bi, Cp, coeff, stepd);
  wprep_kernel<<<dim3(16, 16, 4), 256, 0, stream>>>(outW, WtHi, WtLo);
  if (kfAll) kfft_kernel<<<4 * kH, 256, 0, stream>>>(coeff, stepd, twst, Kf);

  const int nchunk = kB / CB;
  for (int c = 0; c < nchunk; c++) {
    const int b0 = c * CB;
    encoder_kernel<<<CB * kH * (kL / 256), 256, 0, stream>>>(
        seq + (size_t)b0 * kL * 5, encW, encb, X);
    for (int layer = 0; layer < 4; layer++) {
      if (!kfAll)
        kfft_kernel<<<kH, 256, 0, stream>>>(
            coeff + (size_t)layer * kH * kN, stepd + (size_t)layer * kH * kN,
            twst, Kf);
      ln_stats_kernel<<<CB * (kL / 64), 256, 0, stream>>>(X, mu, rstd);
      conv_kernel<<<CB * kH, 256, 0, stream>>>(
          X, mu, rstd, lng + layer * kH, lnb + layer * kH, Dp + layer * kH,
          kfAll ? Kf + (size_t)layer * kH * 2049 : Kf, twst, Yb);
      ytrans_kernel<<<dim3(kL / 64, kH / 64, CB), 256, 0, stream>>>(Yb, YtHi, YtLo);
      gemm_mfma_kernel<<<dim3(4, kL / 128, CB), 256, 0, stream>>>(
          WtHi + (size_t)layer * kH * kH, WtLo + (size_t)layer * kH * kH,
          YtHi, YtLo, outb + layer * kH, X);
    }
    pool_kernel<<<CB * kH, 256, 0, stream>>>(X, pooled + (size_t)b0 * kH);
  }

  head_kernel<<<kB, 256, 0, stream>>>(pooled, com, cou, comE, couE, fusW, fusb,
                                      vW1, vb1, vW2, vb2, wW1, wb1, wW2, wb2, out);
}